// Round 1
// baseline (2389.906 us; speedup 1.0000x reference)
//
#include <hip/hip_runtime.h>
#include <math.h>

#define NN 50000
#define DD 128
#define EE 800000

// ---------------- small kernels ----------------

__global__ void k_zero(float* __restrict__ p, int n) {
    int i = blockIdx.x * 256 + threadIdx.x;
    if (i < n) p[i] = 0.f;
}

__global__ void k_deg(const int* __restrict__ dst, float* __restrict__ deg) {
    int e = blockIdx.x * 256 + threadIdx.x;
    if (e < EE) unsafeAtomicAdd(&deg[dst[e]], 1.0f);
}

__global__ void k_dinv(float* __restrict__ deg) {
    int n = blockIdx.x * 256 + threadIdx.x;
    if (n < NN) deg[n] = rsqrtf(deg[n] + 1.0f);  // +1 for self-loop
}

// AX[n] = dinv[n]^2 * X[n]   (self-loop term initializes the accumulator)
__global__ void k_axinit(const float* __restrict__ X, const float* __restrict__ dinv,
                         float* __restrict__ AX) {
    int i = blockIdx.x * 256 + threadIdx.x;   // float4 index
    if (i < NN * 32) {
        int n = i >> 5;
        float s = dinv[n]; s *= s;
        float4 v = ((const float4*)X)[i];
        v.x *= s; v.y *= s; v.z *= s; v.w *= s;
        ((float4*)AX)[i] = v;
    }
}

// AX[dst] += dinv[src]*dinv[dst] * X[src]  — 32 lanes per edge, float4 each
__global__ void k_edge(const float* __restrict__ X, const int* __restrict__ src,
                       const int* __restrict__ dst, const float* __restrict__ dinv,
                       float* __restrict__ AX) {
    int t = blockIdx.x * 256 + threadIdx.x;
    int e = t >> 5, l = t & 31;
    if (e < EE) {
        int s = src[e], d = dst[e];
        float c = dinv[s] * dinv[d];
        float4 v = ((const float4*)(X + (size_t)s * DD))[l];
        float* o = AX + (size_t)d * DD + l * 4;
        unsafeAtomicAdd(o + 0, c * v.x);
        unsafeAtomicAdd(o + 1, c * v.y);
        unsafeAtomicAdd(o + 2, c * v.z);
        unsafeAtomicAdd(o + 3, c * v.w);
    }
}

// ---------------- weight prep ----------------
// WAT[c][k], c in [0,256), k in [0,256), stride 256 (transposed for float4 k-reads):
//   k<128:  U_g[k][c%128] = sum_j Wc_g[k][j] * Wl_g[j][c%128]   (g = z if c<128 else r)
//   k>=128: Wl_g[k][c%128]  (bottom half of Wl multiplies h)
// WBT[c][k], c in [0,128), k in [0,256): gate hh, bottom half multiplies h*R
// WLT[c][k], c,k in [0,128): W_lin transposed
// bA[c] = bc_g @ Wl_g_top + bl_g ; bB[c] = bc_hh @ Wl_hh_top + bl_hh
__global__ void k_prep(const float* __restrict__ Wc_z, const float* __restrict__ Wl_z,
                       const float* __restrict__ bc_z, const float* __restrict__ bl_z,
                       const float* __restrict__ Wc_r, const float* __restrict__ Wl_r,
                       const float* __restrict__ bc_r, const float* __restrict__ bl_r,
                       const float* __restrict__ Wc_h, const float* __restrict__ Wl_h,
                       const float* __restrict__ bc_h, const float* __restrict__ bl_h,
                       const float* __restrict__ W_lin, const float* __restrict__ b_lin,
                       float* __restrict__ WAT, float* __restrict__ WBT,
                       float* __restrict__ WLT, float* __restrict__ bA,
                       float* __restrict__ bB) {
    int idx = blockIdx.x * 256 + threadIdx.x;
    if (idx < 65536) {
        int c = idx >> 8, k = idx & 255, cc = c & 127;
        const float* Wc = (c < 128) ? Wc_z : Wc_r;
        const float* Wl = (c < 128) ? Wl_z : Wl_r;
        float v;
        if (k < 128) {
            float s = 0.f;
            for (int j = 0; j < 128; j++) s += Wc[k * 128 + j] * Wl[j * 128 + cc];
            v = s;
        } else {
            v = Wl[k * 128 + cc];
        }
        WAT[idx] = v;
    } else if (idx < 98304) {
        int i2 = idx - 65536;
        int c = i2 >> 8, k = i2 & 255;
        float v;
        if (k < 128) {
            float s = 0.f;
            for (int j = 0; j < 128; j++) s += Wc_h[k * 128 + j] * Wl_h[j * 128 + c];
            v = s;
        } else {
            v = Wl_h[k * 128 + c];
        }
        WBT[i2] = v;
    } else if (idx < 114688) {
        int i3 = idx - 98304;
        int c = i3 >> 7, k = i3 & 127;
        WLT[i3] = W_lin[k * 128 + c];
    } else if (idx < 114944) {
        int c = idx - 114688, cc = c & 127;
        const float* bc = (c < 128) ? bc_z : bc_r;
        const float* Wl = (c < 128) ? Wl_z : Wl_r;
        const float* bl = (c < 128) ? bl_z : bl_r;
        float s = bl[cc];
        for (int j = 0; j < 128; j++) s += bc[j] * Wl[j * 128 + cc];
        bA[c] = s;
    } else if (idx < 115072) {
        int c = idx - 114944;
        float s = bl_h[c];
        for (int j = 0; j < 128; j++) s += bc_h[j] * Wl_h[j * 128 + c];
        bB[c] = s;
    }
}

// ---------------- GEMM A: [Z|R] = sigmoid([AX|h] @ WA + bA) ----------------
// 64 rows/block, 256 cols. Threads: 16x16, each thread 4 rows x 16 strided cols.
__global__ __launch_bounds__(256) void k_gemmA(const float* __restrict__ AX,
                                               const float* __restrict__ h,
                                               const float* __restrict__ WAT,
                                               const float* __restrict__ bA,
                                               float* __restrict__ Zb,
                                               float* __restrict__ hRb) {
    __shared__ float As[64 * 256];   // [row][k] k<128: AX, k>=128: h  (64 KB)
    const int row0 = blockIdx.x * 64;
    const int tid = threadIdx.x;

    // stage 64 rows x 256 K = 4096 float4, 16 per thread
    #pragma unroll
    for (int i = 0; i < 16; i++) {
        int slot = tid + 256 * i;
        int r = slot >> 6;
        int q = slot & 63;           // 0..31 AX, 32..63 h
        int part = q >> 5, kq = q & 31;
        float4 v = make_float4(0.f, 0.f, 0.f, 0.f);
        int gr = row0 + r;
        if (gr < NN) {
            const float* sp = part ? h : AX;
            v = ((const float4*)(sp + (size_t)gr * DD))[kq];
        }
        *((float4*)&As[r * 256 + part * 128 + kq * 4]) = v;
    }
    __syncthreads();

    const int tx = tid & 15, ty = tid >> 4;
    float acc[4][16];
    #pragma unroll
    for (int i = 0; i < 4; i++)
        #pragma unroll
        for (int j = 0; j < 16; j++) acc[i][j] = 0.f;

    for (int k4 = 0; k4 < 64; k4++) {
        float4 a[4];
        #pragma unroll
        for (int i = 0; i < 4; i++)
            a[i] = *((const float4*)&As[(ty * 4 + i) * 256 + k4 * 4]);
        #pragma unroll
        for (int j = 0; j < 16; j++) {
            int c = tx + 16 * j;
            float4 w = *((const float4*)(WAT + ((size_t)c << 8)) + k4);
            #pragma unroll
            for (int i = 0; i < 4; i++)
                acc[i][j] += a[i].x * w.x + a[i].y * w.y + a[i].z * w.z + a[i].w * w.w;
        }
    }

    // epilogue: sigmoid; c<128 -> Z, c>=128 -> h*R
    #pragma unroll
    for (int i = 0; i < 4; i++) {
        int r = ty * 4 + i, gr = row0 + r;
        if (gr < NN) {
            #pragma unroll
            for (int j = 0; j < 16; j++) {
                int c = tx + 16 * j;
                float g = acc[i][j] + bA[c];
                float sg = 1.f / (1.f + expf(-g));
                if (c < 128) {
                    Zb[(size_t)gr * DD + c] = sg;
                } else {
                    int cc = c - 128;
                    float hv = As[r * 256 + 128 + cc];
                    hRb[(size_t)gr * DD + cc] = hv * sg;
                }
            }
        }
    }
}

// ---------------- GEMM B+C fused ----------------
// gh = [AX|hR] @ WB + bB ; H=tanh(gh); h0 = Z*h+(1-Z)*H -> out_h
// z_out = relu(h0) @ WLT + b_lin -> out_z
__global__ __launch_bounds__(256) void k_gemmBC(const float* __restrict__ AX,
                                                const float* __restrict__ hRb,
                                                const float* __restrict__ h,
                                                const float* __restrict__ Zb,
                                                const float* __restrict__ WBT,
                                                const float* __restrict__ bB,
                                                const float* __restrict__ WLT,
                                                const float* __restrict__ b_lin,
                                                float* __restrict__ out_z,
                                                float* __restrict__ out_h) {
    __shared__ float As[64 * 256];
    const int row0 = blockIdx.x * 64;
    const int tid = threadIdx.x;

    #pragma unroll
    for (int i = 0; i < 16; i++) {
        int slot = tid + 256 * i;
        int r = slot >> 6;
        int q = slot & 63;
        int part = q >> 5, kq = q & 31;
        float4 v = make_float4(0.f, 0.f, 0.f, 0.f);
        int gr = row0 + r;
        if (gr < NN) {
            const float* sp = part ? hRb : AX;
            v = ((const float4*)(sp + (size_t)gr * DD))[kq];
        }
        *((float4*)&As[r * 256 + part * 128 + kq * 4]) = v;
    }
    __syncthreads();

    const int tx = tid & 15, ty = tid >> 4;
    float acc[4][8];
    #pragma unroll
    for (int i = 0; i < 4; i++)
        #pragma unroll
        for (int j = 0; j < 8; j++) acc[i][j] = 0.f;

    for (int k4 = 0; k4 < 64; k4++) {
        float4 a[4];
        #pragma unroll
        for (int i = 0; i < 4; i++)
            a[i] = *((const float4*)&As[(ty * 4 + i) * 256 + k4 * 4]);
        #pragma unroll
        for (int j = 0; j < 8; j++) {
            int c = tx + 16 * j;
            float4 w = *((const float4*)(WBT + ((size_t)c << 8)) + k4);
            #pragma unroll
            for (int i = 0; i < 4; i++)
                acc[i][j] += a[i].x * w.x + a[i].y * w.y + a[i].z * w.z + a[i].w * w.w;
        }
    }

    // epilogue 1: H~, h0, write out_h; keep relu(h0)
    float h0v[4][8];
    #pragma unroll
    for (int i = 0; i < 4; i++) {
        int r = ty * 4 + i, gr = row0 + r;
        #pragma unroll
        for (int j = 0; j < 8; j++) {
            int c = tx + 16 * j;
            float rv = 0.f;
            if (gr < NN) {
                float g = acc[i][j] + bB[c];
                float H = tanhf(g);
                float Zv = Zb[(size_t)gr * DD + c];
                float hv = h[(size_t)gr * DD + c];
                float h0 = Zv * hv + (1.f - Zv) * H;
                out_h[(size_t)gr * DD + c] = h0;
                rv = fmaxf(h0, 0.f);
            }
            h0v[i][j] = rv;
        }
    }
    __syncthreads();   // As K-loop reads done everywhere

    // stash relu rows: reuse As as [64][132]
    #pragma unroll
    for (int i = 0; i < 4; i++) {
        int r = ty * 4 + i;
        #pragma unroll
        for (int j = 0; j < 8; j++) {
            int c = tx + 16 * j;
            As[r * 132 + c] = h0v[i][j];
        }
    }
    __syncthreads();

    // phase 2: z_out = relu(h0) @ WLT + b_lin   (K=128)
    float acc2[4][8];
    #pragma unroll
    for (int i = 0; i < 4; i++)
        #pragma unroll
        for (int j = 0; j < 8; j++) acc2[i][j] = 0.f;

    for (int k4 = 0; k4 < 32; k4++) {
        float4 a[4];
        #pragma unroll
        for (int i = 0; i < 4; i++)
            a[i] = *((const float4*)&As[(ty * 4 + i) * 132 + k4 * 4]);
        #pragma unroll
        for (int j = 0; j < 8; j++) {
            int c = tx + 16 * j;
            float4 w = *((const float4*)(WLT + ((size_t)c << 7)) + k4);
            #pragma unroll
            for (int i = 0; i < 4; i++)
                acc2[i][j] += a[i].x * w.x + a[i].y * w.y + a[i].z * w.z + a[i].w * w.w;
        }
    }

    #pragma unroll
    for (int i = 0; i < 4; i++) {
        int r = ty * 4 + i, gr = row0 + r;
        if (gr < NN) {
            #pragma unroll
            for (int j = 0; j < 8; j++) {
                int c = tx + 16 * j;
                out_z[(size_t)gr * DD + c] = acc2[i][j] + b_lin[c];
            }
        }
    }
}

// ---------------- launch ----------------

extern "C" void kernel_launch(void* const* d_in, const int* in_sizes, int n_in,
                              void* d_out, int out_size, void* d_ws, size_t ws_size,
                              hipStream_t stream) {
    const float* X    = (const float*)d_in[0];
    const int*   src  = (const int*)d_in[1];
    const int*   dst  = (const int*)d_in[2];
    const float* h    = (const float*)d_in[3];
    const float* Wc_z = (const float*)d_in[4];
    const float* bc_z = (const float*)d_in[5];
    const float* Wl_z = (const float*)d_in[6];
    const float* bl_z = (const float*)d_in[7];
    const float* Wc_r = (const float*)d_in[8];
    const float* bc_r = (const float*)d_in[9];
    const float* Wl_r = (const float*)d_in[10];
    const float* bl_r = (const float*)d_in[11];
    const float* Wc_h = (const float*)d_in[12];
    const float* bc_h = (const float*)d_in[13];
    const float* Wl_h = (const float*)d_in[14];
    const float* bl_h = (const float*)d_in[15];
    const float* W_lin = (const float*)d_in[16];
    const float* b_lin = (const float*)d_in[17];

    float* out_z = (float*)d_out;              // z_out [N,128]
    float* out_h = out_z + (size_t)NN * DD;    // h_0   [N,128]
    float* AX = out_h;                         // AX aliases out_h (overwritten in gemmBC, block-local order)
    float* Zb = out_z;                         // Z aliases out_z (overwritten in gemmBC phase 2)

    float* ws   = (float*)d_ws;
    float* dinv = ws;                          // 50048
    float* hRb  = ws + 50048;                  // 6,400,000
    float* WAT  = ws + 6450048;                // 65536
    float* WBT  = ws + 6515584;                // 32768
    float* WLT  = ws + 6548352;                // 16384
    float* bA   = ws + 6564736;                // 256
    float* bB   = ws + 6564992;                // 128

    k_prep<<<450, 256, 0, stream>>>(Wc_z, Wl_z, bc_z, bl_z, Wc_r, Wl_r, bc_r, bl_r,
                                    Wc_h, Wl_h, bc_h, bl_h, W_lin, b_lin,
                                    WAT, WBT, WLT, bA, bB);
    k_zero<<<196, 256, 0, stream>>>(dinv, NN);
    k_deg<<<3125, 256, 0, stream>>>(dst, dinv);
    k_dinv<<<196, 256, 0, stream>>>(dinv);
    k_axinit<<<6250, 256, 0, stream>>>(X, dinv, AX);
    k_edge<<<100000, 256, 0, stream>>>(X, src, dst, dinv, AX);
    k_gemmA<<<782, 256, 0, stream>>>(AX, h, WAT, bA, Zb, hRb);
    k_gemmBC<<<782, 256, 0, stream>>>(AX, hRb, h, Zb, WBT, bB, WLT, b_lin, out_z, out_h);
}

// Round 2
// 1080.275 us; speedup vs baseline: 2.2123x; 2.2123x over previous
//
#include <hip/hip_runtime.h>
#include <math.h>

#define NN 50000
#define DD 128
#define EE 800000

// ---------------- CSR build ----------------

__global__ void k_zero_int(int* __restrict__ p, int n) {
    int i = blockIdx.x * 256 + threadIdx.x;
    if (i < n) p[i] = 0;
}

__global__ void k_deg(const int* __restrict__ dst, int* __restrict__ deg) {
    int e = blockIdx.x * 256 + threadIdx.x;
    if (e < EE) atomicAdd(&deg[dst[e]], 1);
}

// off[n] via wave-scan + one atomic per wave; also dinv[n] = rsqrt(deg+1)
__global__ void k_alloc(const int* __restrict__ deg, int* __restrict__ off,
                        int* __restrict__ cursor, float* __restrict__ dinv) {
    int n = blockIdx.x * 256 + threadIdx.x;
    int lane = threadIdx.x & 63;
    int d = (n < NN) ? deg[n] : 0;
    int x = d;
    #pragma unroll
    for (int o = 1; o < 64; o <<= 1) {
        int y = __shfl_up(x, o);
        if (lane >= o) x += y;
    }
    int total = __shfl(x, 63);
    int base = 0;
    if (lane == 0) base = atomicAdd(cursor, total);
    base = __shfl(base, 0);
    if (n < NN) {
        off[n] = base + x - d;           // exclusive scan position
        dinv[n] = rsqrtf((float)d + 1.0f);
    }
}

__global__ void k_fill(const int* __restrict__ src, const int* __restrict__ dst,
                       const int* __restrict__ off, int* __restrict__ cur,
                       int* __restrict__ csr) {
    int e = blockIdx.x * 256 + threadIdx.x;
    if (e < EE) {
        int d = dst[e];
        int slot = atomicAdd(&cur[d], 1);
        csr[off[d] + slot] = src[e];
    }
}

// ---------------- gather: AX[n] = dinv[n]^2 X[n] + sum_e dinv[s]dinv[n] X[s]
__global__ __launch_bounds__(256) void k_gather(const float* __restrict__ X,
                                                const int* __restrict__ csr,
                                                const int* __restrict__ off,
                                                const int* __restrict__ deg,
                                                const float* __restrict__ dinv,
                                                float* __restrict__ AX) {
    int tid = blockIdx.x * 256 + threadIdx.x;
    int n = tid >> 6, lane = tid & 63;
    if (n >= NN) return;
    const float2* X2 = (const float2*)X;
    float dd = dinv[n];
    float2 a = X2[(size_t)n * 64 + lane];
    float acc0 = dd * dd * a.x, acc1 = dd * dd * a.y;
    int o = off[n], cnt = deg[n];
    int i = 0;
    for (; i + 4 <= cnt; i += 4) {
        int s0 = csr[o + i], s1 = csr[o + i + 1], s2 = csr[o + i + 2], s3 = csr[o + i + 3];
        float c0 = dinv[s0] * dd, c1 = dinv[s1] * dd;
        float c2 = dinv[s2] * dd, c3 = dinv[s3] * dd;
        float2 v0 = X2[(size_t)s0 * 64 + lane];
        float2 v1 = X2[(size_t)s1 * 64 + lane];
        float2 v2 = X2[(size_t)s2 * 64 + lane];
        float2 v3 = X2[(size_t)s3 * 64 + lane];
        acc0 += c0 * v0.x + c1 * v1.x + c2 * v2.x + c3 * v3.x;
        acc1 += c0 * v0.y + c1 * v1.y + c2 * v2.y + c3 * v3.y;
    }
    for (; i < cnt; i++) {
        int s = csr[o + i];
        float c = dinv[s] * dd;
        float2 v = X2[(size_t)s * 64 + lane];
        acc0 += c * v.x;
        acc1 += c * v.y;
    }
    ((float2*)AX)[(size_t)n * 64 + lane] = make_float2(acc0, acc1);
}

// ---------------- weight prep (same as R1) ----------------
__global__ void k_prep(const float* __restrict__ Wc_z, const float* __restrict__ Wl_z,
                       const float* __restrict__ bc_z, const float* __restrict__ bl_z,
                       const float* __restrict__ Wc_r, const float* __restrict__ Wl_r,
                       const float* __restrict__ bc_r, const float* __restrict__ bl_r,
                       const float* __restrict__ Wc_h, const float* __restrict__ Wl_h,
                       const float* __restrict__ bc_h, const float* __restrict__ bl_h,
                       const float* __restrict__ W_lin, const float* __restrict__ b_lin,
                       float* __restrict__ WAT, float* __restrict__ WBT,
                       float* __restrict__ WLT, float* __restrict__ bA,
                       float* __restrict__ bB) {
    int idx = blockIdx.x * 256 + threadIdx.x;
    if (idx < 65536) {
        int c = idx >> 8, k = idx & 255, cc = c & 127;
        const float* Wc = (c < 128) ? Wc_z : Wc_r;
        const float* Wl = (c < 128) ? Wl_z : Wl_r;
        float v;
        if (k < 128) {
            float s = 0.f;
            for (int j = 0; j < 128; j++) s += Wc[k * 128 + j] * Wl[j * 128 + cc];
            v = s;
        } else {
            v = Wl[k * 128 + cc];
        }
        WAT[idx] = v;
    } else if (idx < 98304) {
        int i2 = idx - 65536;
        int c = i2 >> 8, k = i2 & 255;
        float v;
        if (k < 128) {
            float s = 0.f;
            for (int j = 0; j < 128; j++) s += Wc_h[k * 128 + j] * Wl_h[j * 128 + c];
            v = s;
        } else {
            v = Wl_h[k * 128 + c];
        }
        WBT[i2] = v;
    } else if (idx < 114688) {
        int i3 = idx - 98304;
        int c = i3 >> 7, k = i3 & 127;
        WLT[i3] = W_lin[k * 128 + c];
    } else if (idx < 114944) {
        int c = idx - 114688, cc = c & 127;
        const float* bc = (c < 128) ? bc_z : bc_r;
        const float* Wl = (c < 128) ? Wl_z : Wl_r;
        const float* bl = (c < 128) ? bl_z : bl_r;
        float s = bl[cc];
        for (int j = 0; j < 128; j++) s += bc[j] * Wl[j * 128 + cc];
        bA[c] = s;
    } else if (idx < 115072) {
        int c = idx - 114944;
        float s = bl_h[c];
        for (int j = 0; j < 128; j++) s += bc_h[j] * Wl_h[j * 128 + c];
        bB[c] = s;
    }
}

// ---------------- fully fused node-wise kernel ----------------
// Phase A: [Z|R] = sigmoid([AX|h] @ WAT + bA)    (K=256, 256 cols)
// in-place: LDS h-half <- h*R
// Phase B: H~ = tanh([AX|hR] @ WBT + bB); h0 = Z*h + (1-Z)*H~ -> out_h
// Phase C: z_out = relu(h0) @ WLT + b_lin -> out_z
__global__ __launch_bounds__(256) void k_fused(const float* __restrict__ AX,
                                               const float* __restrict__ h,
                                               const float* __restrict__ WAT,
                                               const float* __restrict__ bA,
                                               const float* __restrict__ WBT,
                                               const float* __restrict__ bB,
                                               const float* __restrict__ WLT,
                                               const float* __restrict__ b_lin,
                                               float* __restrict__ out_z,
                                               float* __restrict__ out_h) {
    __shared__ float As[64 * 256];   // 64 KB: [row][k]  k<128: AX, k>=128: h (later h*R)
    const int row0 = blockIdx.x * 64;
    const int tid = threadIdx.x;

    // stage 64 rows x 256 K
    #pragma unroll
    for (int i = 0; i < 16; i++) {
        int slot = tid + 256 * i;
        int r = slot >> 6;
        int q = slot & 63;
        int part = q >> 5, kq = q & 31;
        float4 v = make_float4(0.f, 0.f, 0.f, 0.f);
        int gr = row0 + r;
        if (gr < NN) {
            const float* sp = part ? h : AX;
            v = ((const float4*)(sp + (size_t)gr * DD))[kq];
        }
        *((float4*)&As[r * 256 + part * 128 + kq * 4]) = v;
    }
    __syncthreads();

    const int tx = tid & 15, ty = tid >> 4;

    // ---- phase A ----
    float accA[4][16];
    #pragma unroll
    for (int i = 0; i < 4; i++)
        #pragma unroll
        for (int j = 0; j < 16; j++) accA[i][j] = 0.f;

    for (int k4 = 0; k4 < 64; k4++) {
        float4 a[4];
        #pragma unroll
        for (int i = 0; i < 4; i++)
            a[i] = *((const float4*)&As[(ty * 4 + i) * 256 + k4 * 4]);
        #pragma unroll
        for (int j = 0; j < 16; j++) {
            int c = tx + 16 * j;
            float4 w = *((const float4*)(WAT + ((size_t)c << 8)) + k4);
            #pragma unroll
            for (int i = 0; i < 4; i++)
                accA[i][j] += a[i].x * w.x + a[i].y * w.y + a[i].z * w.z + a[i].w * w.w;
        }
    }

    float Zv[4][8], hv[4][8], hRv[4][8];
    #pragma unroll
    for (int i = 0; i < 4; i++) {
        int r = ty * 4 + i;
        #pragma unroll
        for (int j = 0; j < 16; j++) {
            int c = tx + 16 * j;
            float g = accA[i][j] + bA[c];
            float sg = 1.f / (1.f + expf(-g));
            if (j < 8) {
                Zv[i][j] = sg;
            } else {
                float hval = As[r * 256 + c];    // c>=128: the h half
                hv[i][j - 8] = hval;
                hRv[i][j - 8] = hval * sg;
            }
        }
    }
    __syncthreads();   // everyone done READING As (K-loop + h reads)

    // in-place: h-half of As <- h*R
    #pragma unroll
    for (int i = 0; i < 4; i++) {
        int r = ty * 4 + i;
        #pragma unroll
        for (int j = 0; j < 8; j++) {
            int c = tx + 16 * j + 128;
            As[r * 256 + c] = hRv[i][j];
        }
    }
    __syncthreads();

    // ---- phase B ----
    float accB[4][8];
    #pragma unroll
    for (int i = 0; i < 4; i++)
        #pragma unroll
        for (int j = 0; j < 8; j++) accB[i][j] = 0.f;

    for (int k4 = 0; k4 < 64; k4++) {
        float4 a[4];
        #pragma unroll
        for (int i = 0; i < 4; i++)
            a[i] = *((const float4*)&As[(ty * 4 + i) * 256 + k4 * 4]);
        #pragma unroll
        for (int j = 0; j < 8; j++) {
            int c = tx + 16 * j;
            float4 w = *((const float4*)(WBT + ((size_t)c << 8)) + k4);
            #pragma unroll
            for (int i = 0; i < 4; i++)
                accB[i][j] += a[i].x * w.x + a[i].y * w.y + a[i].z * w.z + a[i].w * w.w;
        }
    }

    float rl[4][8];
    #pragma unroll
    for (int i = 0; i < 4; i++) {
        int r = ty * 4 + i, gr = row0 + r;
        #pragma unroll
        for (int j = 0; j < 8; j++) {
            int cc = tx + 16 * j;
            float g = accB[i][j] + bB[cc];
            float H = tanhf(g);
            float Zg = Zv[i][j];
            float h0 = Zg * hv[i][j] + (1.f - Zg) * H;
            if (gr < NN) out_h[(size_t)gr * DD + cc] = h0;
            rl[i][j] = fmaxf(h0, 0.f);
        }
    }
    __syncthreads();   // phase B As reads done

    // stash relu(h0) rows: reuse As as [64][132]
    #pragma unroll
    for (int i = 0; i < 4; i++) {
        int r = ty * 4 + i;
        #pragma unroll
        for (int j = 0; j < 8; j++) {
            int cc = tx + 16 * j;
            As[r * 132 + cc] = rl[i][j];
        }
    }
    __syncthreads();

    // ---- phase C ----
    float accC[4][8];
    #pragma unroll
    for (int i = 0; i < 4; i++)
        #pragma unroll
        for (int j = 0; j < 8; j++) accC[i][j] = 0.f;

    for (int k4 = 0; k4 < 32; k4++) {
        float4 a[4];
        #pragma unroll
        for (int i = 0; i < 4; i++)
            a[i] = *((const float4*)&As[(ty * 4 + i) * 132 + k4 * 4]);
        #pragma unroll
        for (int j = 0; j < 8; j++) {
            int c = tx + 16 * j;
            float4 w = *((const float4*)(WLT + ((size_t)c << 7)) + k4);
            #pragma unroll
            for (int i = 0; i < 4; i++)
                accC[i][j] += a[i].x * w.x + a[i].y * w.y + a[i].z * w.z + a[i].w * w.w;
        }
    }

    #pragma unroll
    for (int i = 0; i < 4; i++) {
        int r = ty * 4 + i, gr = row0 + r;
        if (gr < NN) {
            #pragma unroll
            for (int j = 0; j < 8; j++) {
                int c = tx + 16 * j;
                out_z[(size_t)gr * DD + c] = accC[i][j] + b_lin[c];
            }
        }
    }
}

// ---------------- launch ----------------

extern "C" void kernel_launch(void* const* d_in, const int* in_sizes, int n_in,
                              void* d_out, int out_size, void* d_ws, size_t ws_size,
                              hipStream_t stream) {
    const float* X    = (const float*)d_in[0];
    const int*   src  = (const int*)d_in[1];
    const int*   dst  = (const int*)d_in[2];
    const float* h    = (const float*)d_in[3];
    const float* Wc_z = (const float*)d_in[4];
    const float* bc_z = (const float*)d_in[5];
    const float* Wl_z = (const float*)d_in[6];
    const float* bl_z = (const float*)d_in[7];
    const float* Wc_r = (const float*)d_in[8];
    const float* bc_r = (const float*)d_in[9];
    const float* Wl_r = (const float*)d_in[10];
    const float* bl_r = (const float*)d_in[11];
    const float* Wc_h = (const float*)d_in[12];
    const float* bc_h = (const float*)d_in[13];
    const float* Wl_h = (const float*)d_in[14];
    const float* bl_h = (const float*)d_in[15];
    const float* W_lin = (const float*)d_in[16];
    const float* b_lin = (const float*)d_in[17];

    float* out_z = (float*)d_out;              // z_out [N,128]
    float* out_h = out_z + (size_t)NN * DD;    // h_0   [N,128]
    float* AX = out_h;                         // AX aliases out_h (block-local overwrite in k_fused)

    // ws layout (4B words)
    float* ws = (float*)d_ws;
    float* dinv   = ws;                        // 50048 f32
    int*   deg    = (int*)(ws + 50048);        // 50048
    int*   cur    = (int*)(ws + 100096);       // 50048
    int*   cursor = (int*)(ws + 150144);       // 64
    int*   off    = (int*)(ws + 150208);       // 50048
    int*   csr    = (int*)(ws + 200256);       // 800064
    float* WAT    = ws + 1000320;              // 65536
    float* WBT    = ws + 1065856;              // 32768
    float* WLT    = ws + 1098624;              // 16384
    float* bA     = ws + 1115008;              // 256
    float* bB     = ws + 1115264;              // 128

    k_prep<<<450, 256, 0, stream>>>(Wc_z, Wl_z, bc_z, bl_z, Wc_r, Wl_r, bc_r, bl_r,
                                    Wc_h, Wl_h, bc_h, bl_h, W_lin, b_lin,
                                    WAT, WBT, WLT, bA, bB);
    // zero deg, cur, cursor (contiguous: 100160 ints)
    k_zero_int<<<392, 256, 0, stream>>>(deg, 100160);
    k_deg<<<3125, 256, 0, stream>>>(dst, deg);
    k_alloc<<<196, 256, 0, stream>>>(deg, off, cursor, dinv);
    k_fill<<<3125, 256, 0, stream>>>(src, dst, off, cur, csr);
    k_gather<<<12500, 256, 0, stream>>>(X, csr, off, deg, dinv, AX);
    k_fused<<<782, 256, 0, stream>>>(AX, h, WAT, bA, WBT, bB, WLT, b_lin, out_z, out_h);
}

// Round 3
// 431.290 us; speedup vs baseline: 5.5413x; 2.5048x over previous
//
#include <hip/hip_runtime.h>
#include <math.h>

#define NN 50000
#define DD 128
#define EE 800000

typedef __attribute__((ext_vector_type(8))) short short8;
typedef __attribute__((ext_vector_type(4))) float f32x4;

__device__ __forceinline__ ushort f2bf(float f) {
    union { float f; unsigned u; } v; v.f = f;
    unsigned r = v.u + 0x7FFF + ((v.u >> 16) & 1);   // RNE
    return (ushort)(r >> 16);
}

// ---------------- CSR build ----------------

__global__ void k_zero_int(int* __restrict__ p, int n) {
    int i = blockIdx.x * 256 + threadIdx.x;
    if (i < n) p[i] = 0;
}

__global__ void k_deg(const int* __restrict__ dst, int* __restrict__ deg) {
    int e = blockIdx.x * 256 + threadIdx.x;
    if (e < EE) atomicAdd(&deg[dst[e]], 1);
}

__global__ void k_alloc(const int* __restrict__ deg, int* __restrict__ off,
                        int* __restrict__ cursor, float* __restrict__ dinv) {
    int n = blockIdx.x * 256 + threadIdx.x;
    int lane = threadIdx.x & 63;
    int d = (n < NN) ? deg[n] : 0;
    int x = d;
    #pragma unroll
    for (int o = 1; o < 64; o <<= 1) {
        int y = __shfl_up(x, o);
        if (lane >= o) x += y;
    }
    int total = __shfl(x, 63);
    int base = 0;
    if (lane == 0) base = atomicAdd(cursor, total);
    base = __shfl(base, 0);
    if (n < NN) {
        off[n] = base + x - d;
        dinv[n] = rsqrtf((float)d + 1.0f);
    }
}

__global__ void k_fill(const int* __restrict__ src, const int* __restrict__ dst,
                       const int* __restrict__ off, int* __restrict__ cur,
                       int* __restrict__ csr) {
    int e = blockIdx.x * 256 + threadIdx.x;
    if (e < EE) {
        int d = dst[e];
        int slot = atomicAdd(&cur[d], 1);
        csr[off[d] + slot] = src[e];
    }
}

// ---------------- gather -> bf16 AX ----------------
__global__ __launch_bounds__(256) void k_gather(const float* __restrict__ X,
                                                const int* __restrict__ csr,
                                                const int* __restrict__ off,
                                                const int* __restrict__ deg,
                                                const float* __restrict__ dinv,
                                                ushort* __restrict__ AXb) {
    int tid = blockIdx.x * 256 + threadIdx.x;
    int n = tid >> 6, lane = tid & 63;
    if (n >= NN) return;
    const float2* X2 = (const float2*)X;
    float dd = dinv[n];
    float2 a = X2[(size_t)n * 64 + lane];
    float acc0 = dd * dd * a.x, acc1 = dd * dd * a.y;
    int o = off[n], cnt = deg[n];
    int i = 0;
    for (; i + 4 <= cnt; i += 4) {
        int s0 = csr[o + i], s1 = csr[o + i + 1], s2 = csr[o + i + 2], s3 = csr[o + i + 3];
        float c0 = dinv[s0] * dd, c1 = dinv[s1] * dd;
        float c2 = dinv[s2] * dd, c3 = dinv[s3] * dd;
        float2 v0 = X2[(size_t)s0 * 64 + lane];
        float2 v1 = X2[(size_t)s1 * 64 + lane];
        float2 v2 = X2[(size_t)s2 * 64 + lane];
        float2 v3 = X2[(size_t)s3 * 64 + lane];
        acc0 += c0 * v0.x + c1 * v1.x + c2 * v2.x + c3 * v3.x;
        acc1 += c0 * v0.y + c1 * v1.y + c2 * v2.y + c3 * v3.y;
    }
    for (; i < cnt; i++) {
        int s = csr[o + i];
        float c = dinv[s] * dd;
        float2 v = X2[(size_t)s * 64 + lane];
        acc0 += c * v.x;
        acc1 += c * v.y;
    }
    ushort2 u; u.x = f2bf(acc0); u.y = f2bf(acc1);
    *((ushort2*)(AXb + (size_t)n * 128 + lane * 2)) = u;
}

// ---------------- h -> bf16 ----------------
__global__ void k_h2b(const float* __restrict__ h, ushort* __restrict__ hb) {
    int i = blockIdx.x * 256 + threadIdx.x;
    if (i < NN * 32) {
        float4 v = ((const float4*)h)[i];
        ushort4 u;
        u.x = f2bf(v.x); u.y = f2bf(v.y); u.z = f2bf(v.z); u.w = f2bf(v.w);
        ((ushort4*)hb)[i] = u;
    }
}

// ---------------- weight prep (bf16, transposed [col][k]) ----------------
__global__ void k_prep(const float* __restrict__ Wc_z, const float* __restrict__ Wl_z,
                       const float* __restrict__ bc_z, const float* __restrict__ bl_z,
                       const float* __restrict__ Wc_r, const float* __restrict__ Wl_r,
                       const float* __restrict__ bc_r, const float* __restrict__ bl_r,
                       const float* __restrict__ Wc_h, const float* __restrict__ Wl_h,
                       const float* __restrict__ bc_h, const float* __restrict__ bl_h,
                       const float* __restrict__ W_lin,
                       ushort* __restrict__ WA, ushort* __restrict__ WB,
                       ushort* __restrict__ WL, float* __restrict__ bA,
                       float* __restrict__ bB) {
    int idx = blockIdx.x * 256 + threadIdx.x;
    if (idx < 65536) {
        int c = idx >> 8, k = idx & 255, cc = c & 127;
        const float* Wc = (c < 128) ? Wc_z : Wc_r;
        const float* Wl = (c < 128) ? Wl_z : Wl_r;
        float v;
        if (k < 128) {
            float s = 0.f;
            for (int j = 0; j < 128; j++) s += Wc[k * 128 + j] * Wl[j * 128 + cc];
            v = s;
        } else {
            v = Wl[k * 128 + cc];
        }
        WA[idx] = f2bf(v);
    } else if (idx < 98304) {
        int i2 = idx - 65536;
        int c = i2 >> 8, k = i2 & 255;
        float v;
        if (k < 128) {
            float s = 0.f;
            for (int j = 0; j < 128; j++) s += Wc_h[k * 128 + j] * Wl_h[j * 128 + c];
            v = s;
        } else {
            v = Wl_h[k * 128 + c];
        }
        WB[i2] = f2bf(v);
    } else if (idx < 114688) {
        int i3 = idx - 98304;
        int c = i3 >> 7, k = i3 & 127;
        WL[i3] = f2bf(W_lin[k * 128 + c]);
    } else if (idx < 114944) {
        int c = idx - 114688, cc = c & 127;
        const float* bc = (c < 128) ? bc_z : bc_r;
        const float* Wl = (c < 128) ? Wl_z : Wl_r;
        const float* bl = (c < 128) ? bl_z : bl_r;
        float s = bl[cc];
        for (int j = 0; j < 128; j++) s += bc[j] * Wl[j * 128 + cc];
        bA[c] = s;
    } else if (idx < 115072) {
        int c = idx - 114944;
        float s = bl_h[c];
        for (int j = 0; j < 128; j++) s += bc_h[j] * Wl_h[j * 128 + c];
        bB[c] = s;
    }
}

// ---------------- fused MFMA node-wise kernel ----------------
// 64 rows/block, 4 waves; wave w owns rows [w*16, w*16+16).
// LDS: Abuf bf16 [64 rows][256 k], row stride 512B, XOR-swizzled 16B slots.
// Phase A: [Z|R] = sigmoid([AX|h] @ WA + bA)      K=256, 256 cols
// Phase B: H~ = tanh([AX|hR] @ WB + bB); h0 -> out_h
// Phase C: z_out = relu(h0) @ WL + b_lin -> out_z
__global__ __launch_bounds__(256) void k_fused(const ushort* __restrict__ AXb,
                                               const ushort* __restrict__ hb,
                                               const float* __restrict__ h,
                                               const ushort* __restrict__ WA,
                                               const ushort* __restrict__ WB,
                                               const ushort* __restrict__ WL,
                                               const float* __restrict__ bA,
                                               const float* __restrict__ bB,
                                               const float* __restrict__ b_lin,
                                               float* __restrict__ out_z,
                                               float* __restrict__ out_h) {
    __shared__ ushort Abuf[64 * 256];   // 32 KB
    const int tid = threadIdx.x;
    const int row0 = blockIdx.x * 64;

    // ---- stage 64 rows x 256 bf16 (AX | h), swizzled ----
    #pragma unroll
    for (int i = 0; i < 8; i++) {
        int c = tid + 256 * i;           // 16B-chunk id, 0..2047
        int r = c >> 5;                  // 32 chunks per 512B row
        int cq = c & 31, part = cq >> 4, q = cq & 15;
        int gr = row0 + r;
        uint4 v = make_uint4(0u, 0u, 0u, 0u);
        if (gr < NN) {
            const ushort* sp = part ? hb : AXb;
            v = ((const uint4*)(sp + (size_t)gr * 128))[q];
        }
        int db = r * 512 + (((part << 8) + (q << 4)) ^ ((r & 7) << 4));
        *((uint4*)((char*)Abuf + db)) = v;
    }
    __syncthreads();

    const int lane = tid & 63, w = tid >> 6;
    const int tx = lane & 15, g = lane >> 4;
    const int arow = w * 16 + tx;                 // A-frag row (this lane)
    const int aswz = (arow & 7) << 4;
    const char* abase = (const char*)Abuf + arow * 512;
    const int drow = w * 16 + g * 4;              // D rows = drow + r

    // ---- phase A ----
    f32x4 accA[16];
    #pragma unroll
    for (int ct = 0; ct < 16; ct++) accA[ct] = (f32x4){0.f, 0.f, 0.f, 0.f};
    #pragma unroll
    for (int ks = 0; ks < 8; ks++) {
        short8 a = *((const short8*)(abase + ((ks * 64 + g * 16) ^ aswz)));
        int k0 = ks * 32 + g * 8;
        #pragma unroll
        for (int ct = 0; ct < 16; ct++) {
            int col = ct * 16 + tx;
            short8 b = *((const short8*)(WA + ((size_t)col << 8) + k0));
            accA[ct] = __builtin_amdgcn_mfma_f32_16x16x32_bf16(a, b, accA[ct], 0, 0, 0);
        }
    }

    float Zv[8][4], hv[8][4];
    #pragma unroll
    for (int ct = 0; ct < 8; ct++) {
        float bias = bA[ct * 16 + tx];
        #pragma unroll
        for (int r = 0; r < 4; r++)
            Zv[ct][r] = 1.f / (1.f + expf(-(accA[ct][r] + bias)));
    }
    #pragma unroll
    for (int ct = 0; ct < 8; ct++) {
        int cc = ct * 16 + tx;
        float bias = bA[128 + cc];
        #pragma unroll
        for (int r = 0; r < 4; r++) {
            int rr = drow + r, gr = row0 + rr;
            float hval = (gr < NN) ? h[(size_t)gr * 128 + cc] : 0.f;
            hv[ct][r] = hval;
            float R = 1.f / (1.f + expf(-(accA[8 + ct][r] + bias)));
            int db = rr * 512 + ((256 + cc * 2) ^ ((rr & 7) << 4));
            *((ushort*)((char*)Abuf + db)) = f2bf(hval * R);
        }
    }
    __syncthreads();

    // ---- phase B ----
    f32x4 accB[8];
    #pragma unroll
    for (int ct = 0; ct < 8; ct++) accB[ct] = (f32x4){0.f, 0.f, 0.f, 0.f};
    #pragma unroll
    for (int ks = 0; ks < 8; ks++) {
        short8 a = *((const short8*)(abase + ((ks * 64 + g * 16) ^ aswz)));
        int k0 = ks * 32 + g * 8;
        #pragma unroll
        for (int ct = 0; ct < 8; ct++) {
            int col = ct * 16 + tx;
            short8 b = *((const short8*)(WB + ((size_t)col << 8) + k0));
            accB[ct] = __builtin_amdgcn_mfma_f32_16x16x32_bf16(a, b, accB[ct], 0, 0, 0);
        }
    }

    #pragma unroll
    for (int ct = 0; ct < 8; ct++) {
        int col = ct * 16 + tx;
        float bias = bB[col];
        #pragma unroll
        for (int r = 0; r < 4; r++) {
            int rr = drow + r, gr = row0 + rr;
            float gv = accB[ct][r] + bias;
            float H = tanhf(gv);
            float Z = Zv[ct][r];
            float h0 = Z * hv[ct][r] + (1.f - Z) * H;
            if (gr < NN) out_h[(size_t)gr * 128 + col] = h0;
            int db = rr * 512 + ((col * 2) ^ ((rr & 7) << 4));
            *((ushort*)((char*)Abuf + db)) = f2bf(fmaxf(h0, 0.f));
        }
    }
    __syncthreads();

    // ---- phase C ----
    f32x4 accC[8];
    #pragma unroll
    for (int ct = 0; ct < 8; ct++) accC[ct] = (f32x4){0.f, 0.f, 0.f, 0.f};
    #pragma unroll
    for (int ks = 0; ks < 4; ks++) {
        short8 a = *((const short8*)(abase + ((ks * 64 + g * 16) ^ aswz)));
        int k0 = ks * 32 + g * 8;
        #pragma unroll
        for (int ct = 0; ct < 8; ct++) {
            int col = ct * 16 + tx;
            short8 b = *((const short8*)(WL + ((size_t)col << 7) + k0));
            accC[ct] = __builtin_amdgcn_mfma_f32_16x16x32_bf16(a, b, accC[ct], 0, 0, 0);
        }
    }

    #pragma unroll
    for (int ct = 0; ct < 8; ct++) {
        int col = ct * 16 + tx;
        float bias = b_lin[col];
        #pragma unroll
        for (int r = 0; r < 4; r++) {
            int gr = row0 + drow + r;
            if (gr < NN) out_z[(size_t)gr * 128 + col] = accC[ct][r] + bias;
        }
    }
}

// ---------------- launch ----------------

extern "C" void kernel_launch(void* const* d_in, const int* in_sizes, int n_in,
                              void* d_out, int out_size, void* d_ws, size_t ws_size,
                              hipStream_t stream) {
    const float* X    = (const float*)d_in[0];
    const int*   src  = (const int*)d_in[1];
    const int*   dst  = (const int*)d_in[2];
    const float* h    = (const float*)d_in[3];
    const float* Wc_z = (const float*)d_in[4];
    const float* bc_z = (const float*)d_in[5];
    const float* Wl_z = (const float*)d_in[6];
    const float* bl_z = (const float*)d_in[7];
    const float* Wc_r = (const float*)d_in[8];
    const float* bc_r = (const float*)d_in[9];
    const float* Wl_r = (const float*)d_in[10];
    const float* bl_r = (const float*)d_in[11];
    const float* Wc_h = (const float*)d_in[12];
    const float* bc_h = (const float*)d_in[13];
    const float* Wl_h = (const float*)d_in[14];
    const float* bl_h = (const float*)d_in[15];
    const float* W_lin = (const float*)d_in[16];
    const float* b_lin = (const float*)d_in[17];

    float* out_z = (float*)d_out;
    float* out_h = out_z + (size_t)NN * DD;

    // ws layout (4B words)
    float* ws = (float*)d_ws;
    float*  dinv   = ws;                          // 50048
    int*    deg    = (int*)(ws + 50048);          // 50048
    int*    cur    = (int*)(ws + 100096);         // 50048
    int*    cursor = (int*)(ws + 150144);         // 64
    int*    off    = (int*)(ws + 150208);         // 50048
    int*    csr    = (int*)(ws + 200256);         // 800064
    float*  bA     = ws + 1000320;                // 256
    float*  bB     = ws + 1000576;                // 128
    ushort* WA     = (ushort*)(ws + 1000704);     // 65536 bf16
    ushort* WB     = (ushort*)(ws + 1033472);     // 32768 bf16
    ushort* WL     = (ushort*)(ws + 1049856);     // 16384 bf16
    ushort* AXb    = (ushort*)(ws + 1058048);     // 6.4M bf16
    ushort* hb     = (ushort*)(ws + 4258048);     // 6.4M bf16

    k_prep<<<450, 256, 0, stream>>>(Wc_z, Wl_z, bc_z, bl_z, Wc_r, Wl_r, bc_r, bl_r,
                                    Wc_h, Wl_h, bc_h, bl_h, W_lin,
                                    WA, WB, WL, bA, bB);
    k_zero_int<<<392, 256, 0, stream>>>(deg, 100160);   // deg+cur+cursor contiguous
    k_deg<<<3125, 256, 0, stream>>>(dst, deg);
    k_alloc<<<196, 256, 0, stream>>>(deg, off, cursor, dinv);
    k_fill<<<3125, 256, 0, stream>>>(src, dst, off, cur, csr);
    k_h2b<<<6250, 256, 0, stream>>>(h, hb);
    k_gather<<<12500, 256, 0, stream>>>(X, csr, off, deg, dinv, AXb);
    k_fused<<<782, 256, 0, stream>>>(AXb, hb, h, WA, WB, WL, bA, bB, b_lin, out_z, out_h);
}

// Round 4
// 366.065 us; speedup vs baseline: 6.5286x; 1.1782x over previous
//
#include <hip/hip_runtime.h>
#include <math.h>

#define NN 50000
#define DD 128
#define EE 800000

typedef __attribute__((ext_vector_type(8))) short short8;
typedef __attribute__((ext_vector_type(4))) float f32x4;

__device__ __forceinline__ ushort f2bf(float f) {
    union { float f; unsigned u; } v; v.f = f;
    unsigned r = v.u + 0x7FFF + ((v.u >> 16) & 1);   // RNE
    return (ushort)(r >> 16);
}

// ---------------- CSR build ----------------

__global__ void k_zero_int(int* __restrict__ p, int n) {
    int i = blockIdx.x * 256 + threadIdx.x;
    if (i < n) p[i] = 0;
}

__global__ void k_deg(const int* __restrict__ dst, int* __restrict__ deg) {
    int e = blockIdx.x * 256 + threadIdx.x;
    if (e < EE) atomicAdd(&deg[dst[e]], 1);
}

__global__ void k_alloc(const int* __restrict__ deg, int* __restrict__ off,
                        int* __restrict__ cursor, float* __restrict__ dinv) {
    int n = blockIdx.x * 256 + threadIdx.x;
    int lane = threadIdx.x & 63;
    int d = (n < NN) ? deg[n] : 0;
    int x = d;
    #pragma unroll
    for (int o = 1; o < 64; o <<= 1) {
        int y = __shfl_up(x, o);
        if (lane >= o) x += y;
    }
    int total = __shfl(x, 63);
    int base = 0;
    if (lane == 0) base = atomicAdd(cursor, total);
    base = __shfl(base, 0);
    if (n < NN) {
        off[n] = base + x - d;
        dinv[n] = rsqrtf((float)d + 1.0f);
    }
}

__global__ void k_fill(const int* __restrict__ src, const int* __restrict__ dst,
                       const int* __restrict__ off, int* __restrict__ cur,
                       int* __restrict__ csr) {
    int e = blockIdx.x * 256 + threadIdx.x;
    if (e < EE) {
        int d = dst[e];
        int slot = atomicAdd(&cur[d], 1);
        csr[off[d] + slot] = src[e];
    }
}

// ---------------- f32 -> bf16 convert ----------------
__global__ void k_cvt(const float* __restrict__ src, ushort* __restrict__ dst, int n4) {
    int i = blockIdx.x * 256 + threadIdx.x;
    if (i < n4) {
        float4 v = ((const float4*)src)[i];
        ushort4 u;
        u.x = f2bf(v.x); u.y = f2bf(v.y); u.z = f2bf(v.z); u.w = f2bf(v.w);
        ((ushort4*)dst)[i] = u;
    }
}

// ---------------- gather (bf16 X rows, unroll 8) ----------------
__global__ __launch_bounds__(256) void k_gather(const ushort* __restrict__ Xb,
                                                const float* __restrict__ X,
                                                const int* __restrict__ csr,
                                                const int* __restrict__ off,
                                                const int* __restrict__ deg,
                                                const float* __restrict__ dinv,
                                                ushort* __restrict__ AXb) {
    int tid = blockIdx.x * 256 + threadIdx.x;
    int n = tid >> 6, lane = tid & 63;
    if (n >= NN) return;
    float dd = dinv[n];
    float2 a = ((const float2*)X)[(size_t)n * 64 + lane];   // self term in f32
    float acc0 = dd * dd * a.x, acc1 = dd * dd * a.y;
    int o = off[n], cnt = deg[n];
    int i = 0;
    for (; i + 8 <= cnt; i += 8) {
        int s[8];
        #pragma unroll
        for (int u = 0; u < 8; u++) s[u] = csr[o + i + u];
        uint v[8];
        #pragma unroll
        for (int u = 0; u < 8; u++) v[u] = *((const uint*)(Xb + (size_t)s[u] * 128 + lane * 2));
        float c[8];
        #pragma unroll
        for (int u = 0; u < 8; u++) c[u] = dinv[s[u]] * dd;
        #pragma unroll
        for (int u = 0; u < 8; u++) {
            acc0 += c[u] * __uint_as_float(v[u] << 16);
            acc1 += c[u] * __uint_as_float(v[u] & 0xffff0000u);
        }
    }
    for (; i < cnt; i++) {
        int s = csr[o + i];
        float c = dinv[s] * dd;
        uint v = *((const uint*)(Xb + (size_t)s * 128 + lane * 2));
        acc0 += c * __uint_as_float(v << 16);
        acc1 += c * __uint_as_float(v & 0xffff0000u);
    }
    ushort2 u2; u2.x = f2bf(acc0); u2.y = f2bf(acc1);
    *((ushort2*)(AXb + (size_t)n * 128 + lane * 2)) = u2;
}

// ---------------- weight prep: bf16, slice-major [ks][col][kk] ----------------
// WAs: ks 0..7, col 0..255, kk 0..31 (slice = 8192 ushorts)
// WBs: ks 0..7, col 0..127, kk 0..31 (slice = 4096)
// WLs: ks 0..3, col 0..127, kk 0..31 (slice = 4096)
__global__ void k_prep(const float* __restrict__ Wc_z, const float* __restrict__ Wl_z,
                       const float* __restrict__ bc_z, const float* __restrict__ bl_z,
                       const float* __restrict__ Wc_r, const float* __restrict__ Wl_r,
                       const float* __restrict__ bc_r, const float* __restrict__ bl_r,
                       const float* __restrict__ Wc_h, const float* __restrict__ Wl_h,
                       const float* __restrict__ bc_h, const float* __restrict__ bl_h,
                       const float* __restrict__ W_lin,
                       ushort* __restrict__ WAs, ushort* __restrict__ WBs,
                       ushort* __restrict__ WLs, float* __restrict__ bA,
                       float* __restrict__ bB) {
    int idx = blockIdx.x * 256 + threadIdx.x;
    if (idx < 65536) {
        int c = idx >> 8, k = idx & 255, cc = c & 127;
        const float* Wc = (c < 128) ? Wc_z : Wc_r;
        const float* Wl = (c < 128) ? Wl_z : Wl_r;
        float v;
        if (k < 128) {
            float s = 0.f;
            for (int j = 0; j < 128; j++) s += Wc[k * 128 + j] * Wl[j * 128 + cc];
            v = s;
        } else {
            v = Wl[k * 128 + cc];
        }
        WAs[((k >> 5) << 13) + (c << 5) + (k & 31)] = f2bf(v);
    } else if (idx < 98304) {
        int i2 = idx - 65536;
        int c = i2 >> 8, k = i2 & 255;
        float v;
        if (k < 128) {
            float s = 0.f;
            for (int j = 0; j < 128; j++) s += Wc_h[k * 128 + j] * Wl_h[j * 128 + c];
            v = s;
        } else {
            v = Wl_h[k * 128 + c];
        }
        WBs[((k >> 5) << 12) + (c << 5) + (k & 31)] = f2bf(v);
    } else if (idx < 114688) {
        int i3 = idx - 98304;
        int c = i3 >> 7, k = i3 & 127;
        WLs[((k >> 5) << 12) + (c << 5) + (k & 31)] = f2bf(W_lin[k * 128 + c]);
    } else if (idx < 114944) {
        int c = idx - 114688, cc = c & 127;
        const float* bc = (c < 128) ? bc_z : bc_r;
        const float* Wl = (c < 128) ? Wl_z : Wl_r;
        const float* bl = (c < 128) ? bl_z : bl_r;
        float s = bl[cc];
        for (int j = 0; j < 128; j++) s += bc[j] * Wl[j * 128 + cc];
        bA[c] = s;
    } else if (idx < 115072) {
        int c = idx - 114944;
        float s = bl_h[c];
        for (int j = 0; j < 128; j++) s += bc_h[j] * Wl_h[j * 128 + c];
        bB[c] = s;
    }
}

// ---------------- fused MFMA kernel: weights via LDS, A in registers ----------------
// 64 rows/block, 4 waves; wave w owns rows [w*16, w*16+16).
__global__ __launch_bounds__(256) void k_fused(const ushort* __restrict__ AXb,
                                               const ushort* __restrict__ hb,
                                               const float* __restrict__ h,
                                               const ushort* __restrict__ WAs,
                                               const ushort* __restrict__ WBs,
                                               const ushort* __restrict__ WLs,
                                               const float* __restrict__ bA,
                                               const float* __restrict__ bB,
                                               const float* __restrict__ b_lin,
                                               float* __restrict__ out_z,
                                               float* __restrict__ out_h) {
    __shared__ uint4 WbufV[2][1024];                 // 2 x 16 KB weight slices
    __shared__ __align__(16) ushort hRbuf[8192];     // 16 KB: [64 rows][128] bf16, XOR-swizzled

    const int tid = threadIdx.x;
    const int row0 = blockIdx.x * 64;
    const int lane = tid & 63, w = tid >> 6;
    const int tx = lane & 15, g = lane >> 4;
    const int arow = w * 16 + tx;          // A-operand row (this lane)
    const int gar = row0 + arow;
    const int drow = w * 16 + g * 4;       // D rows = drow + r
    const int aswz = (arow & 7) << 4;

    // ---- A-fragments from global (kept in registers) ----
    short8 z8 = {0, 0, 0, 0, 0, 0, 0, 0};
    short8 axf[4], hf[4];
    bool av = (gar < NN);
    #pragma unroll
    for (int ks = 0; ks < 4; ks++) {
        axf[ks] = av ? *((const short8*)(AXb + (size_t)gar * 128 + ks * 32 + g * 8)) : z8;
        hf[ks]  = av ? *((const short8*)(hb  + (size_t)gar * 128 + ks * 32 + g * 8)) : z8;
    }

    uint4 sr[4];
    const uint4* gwA = (const uint4*)WAs;

    // ================= phase A: [Z|R] = sigmoid([AX|h] @ WA + bA) =================
    #pragma unroll
    for (int j = 0; j < 4; j++) sr[j] = gwA[j * 256 + tid];
    #pragma unroll
    for (int j = 0; j < 4; j++) WbufV[0][j * 256 + tid] = sr[j];
    #pragma unroll
    for (int j = 0; j < 4; j++) sr[j] = gwA[1024 + j * 256 + tid];
    __syncthreads();

    f32x4 accA[16];
    #pragma unroll
    for (int ct = 0; ct < 16; ct++) accA[ct] = (f32x4){0.f, 0.f, 0.f, 0.f};

    #pragma unroll
    for (int ks = 0; ks < 8; ks++) {
        const int cur = ks & 1, nxt = cur ^ 1;
        if (ks < 7) {
            #pragma unroll
            for (int j = 0; j < 4; j++) WbufV[nxt][j * 256 + tid] = sr[j];
        }
        if (ks < 6) {
            #pragma unroll
            for (int j = 0; j < 4; j++) sr[j] = gwA[(ks + 2) * 1024 + j * 256 + tid];
        }
        const ushort* wbp = (const ushort*)WbufV[cur];
        short8 a = (ks < 4) ? axf[ks] : hf[ks - 4];
        #pragma unroll
        for (int ct = 0; ct < 16; ct++) {
            short8 b = *((const short8*)(wbp + (ct * 16 + tx) * 32 + g * 8));
            accA[ct] = __builtin_amdgcn_mfma_f32_16x16x32_bf16(a, b, accA[ct], 0, 0, 0);
        }
        __syncthreads();
    }

    // epilogue A: Z kept in regs; hR -> swizzled LDS; h kept in regs
    float Zv[8][4], hv[8][4];
    #pragma unroll
    for (int ct = 0; ct < 8; ct++) {
        float bias = bA[ct * 16 + tx];
        #pragma unroll
        for (int r = 0; r < 4; r++)
            Zv[ct][r] = 1.f / (1.f + expf(-(accA[ct][r] + bias)));
    }
    #pragma unroll
    for (int ct = 0; ct < 8; ct++) {
        int cc = ct * 16 + tx;
        float bias = bA[128 + cc];
        #pragma unroll
        for (int r = 0; r < 4; r++) {
            int rr = drow + r, gr = row0 + rr;
            float hval = (gr < NN) ? h[(size_t)gr * 128 + cc] : 0.f;
            hv[ct][r] = hval;
            float R = 1.f / (1.f + expf(-(accA[8 + ct][r] + bias)));
            *((ushort*)((char*)hRbuf + rr * 256 + ((cc * 2) ^ ((rr & 7) << 4)))) = f2bf(hval * R);
        }
    }

    // ================= phase B: H~ = tanh([AX|hR] @ WB + bB) =================
    const uint4* gwB = (const uint4*)WBs;
    #pragma unroll
    for (int j = 0; j < 2; j++) sr[j] = gwB[j * 256 + tid];
    #pragma unroll
    for (int j = 0; j < 2; j++) WbufV[0][j * 256 + tid] = sr[j];
    #pragma unroll
    for (int j = 0; j < 2; j++) sr[j] = gwB[512 + j * 256 + tid];
    __syncthreads();   // also orders hRbuf writes vs phase-B reads

    f32x4 accB[8];
    #pragma unroll
    for (int ct = 0; ct < 8; ct++) accB[ct] = (f32x4){0.f, 0.f, 0.f, 0.f};

    #pragma unroll
    for (int ks = 0; ks < 8; ks++) {
        const int cur = ks & 1, nxt = cur ^ 1;
        if (ks < 7) {
            #pragma unroll
            for (int j = 0; j < 2; j++) WbufV[nxt][j * 256 + tid] = sr[j];
        }
        if (ks < 6) {
            #pragma unroll
            for (int j = 0; j < 2; j++) sr[j] = gwB[(ks + 2) * 512 + j * 256 + tid];
        }
        const ushort* wbp = (const ushort*)WbufV[cur];
        short8 a;
        if (ks < 4) {
            a = axf[ks];
        } else {
            int kk = ks - 4;
            a = *((const short8*)((const char*)hRbuf + arow * 256 + ((kk * 64 + g * 16) ^ aswz)));
        }
        #pragma unroll
        for (int ct = 0; ct < 8; ct++) {
            short8 b = *((const short8*)(wbp + (ct * 16 + tx) * 32 + g * 8));
            accB[ct] = __builtin_amdgcn_mfma_f32_16x16x32_bf16(a, b, accB[ct], 0, 0, 0);
        }
        __syncthreads();
    }

    // epilogue B: h0 -> out_h; relu(h0) -> hRbuf (all phase-B reads are behind the last barrier)
    #pragma unroll
    for (int ct = 0; ct < 8; ct++) {
        int cc = ct * 16 + tx;
        float bias = bB[cc];
        #pragma unroll
        for (int r = 0; r < 4; r++) {
            int rr = drow + r, gr = row0 + rr;
            float gv = accB[ct][r] + bias;
            float H = tanhf(gv);
            float Z = Zv[ct][r];
            float h0 = Z * hv[ct][r] + (1.f - Z) * H;
            if (gr < NN) out_h[(size_t)gr * 128 + cc] = h0;
            *((ushort*)((char*)hRbuf + rr * 256 + ((cc * 2) ^ ((rr & 7) << 4)))) = f2bf(fmaxf(h0, 0.f));
        }
    }

    // ================= phase C: z_out = relu(h0) @ WL + b_lin =================
    const uint4* gwL = (const uint4*)WLs;
    #pragma unroll
    for (int j = 0; j < 2; j++) sr[j] = gwL[j * 256 + tid];
    #pragma unroll
    for (int j = 0; j < 2; j++) WbufV[0][j * 256 + tid] = sr[j];
    #pragma unroll
    for (int j = 0; j < 2; j++) sr[j] = gwL[512 + j * 256 + tid];
    __syncthreads();   // orders relu writes vs phase-C reads

    f32x4 accC[8];
    #pragma unroll
    for (int ct = 0; ct < 8; ct++) accC[ct] = (f32x4){0.f, 0.f, 0.f, 0.f};

    #pragma unroll
    for (int ks = 0; ks < 4; ks++) {
        const int cur = ks & 1, nxt = cur ^ 1;
        if (ks < 3) {
            #pragma unroll
            for (int j = 0; j < 2; j++) WbufV[nxt][j * 256 + tid] = sr[j];
        }
        if (ks < 2) {
            #pragma unroll
            for (int j = 0; j < 2; j++) sr[j] = gwL[(ks + 2) * 512 + j * 256 + tid];
        }
        const ushort* wbp = (const ushort*)WbufV[cur];
        short8 a = *((const short8*)((const char*)hRbuf + arow * 256 + ((ks * 64 + g * 16) ^ aswz)));
        #pragma unroll
        for (int ct = 0; ct < 8; ct++) {
            short8 b = *((const short8*)(wbp + (ct * 16 + tx) * 32 + g * 8));
            accC[ct] = __builtin_amdgcn_mfma_f32_16x16x32_bf16(a, b, accC[ct], 0, 0, 0);
        }
        __syncthreads();
    }

    #pragma unroll
    for (int ct = 0; ct < 8; ct++) {
        int cc = ct * 16 + tx;
        float bias = b_lin[cc];
        #pragma unroll
        for (int r = 0; r < 4; r++) {
            int gr = row0 + drow + r;
            if (gr < NN) out_z[(size_t)gr * 128 + cc] = accC[ct][r] + bias;
        }
    }
}

// ---------------- launch ----------------

extern "C" void kernel_launch(void* const* d_in, const int* in_sizes, int n_in,
                              void* d_out, int out_size, void* d_ws, size_t ws_size,
                              hipStream_t stream) {
    const float* X    = (const float*)d_in[0];
    const int*   src  = (const int*)d_in[1];
    const int*   dst  = (const int*)d_in[2];
    const float* h    = (const float*)d_in[3];
    const float* Wc_z = (const float*)d_in[4];
    const float* bc_z = (const float*)d_in[5];
    const float* Wl_z = (const float*)d_in[6];
    const float* bl_z = (const float*)d_in[7];
    const float* Wc_r = (const float*)d_in[8];
    const float* bc_r = (const float*)d_in[9];
    const float* Wl_r = (const float*)d_in[10];
    const float* bl_r = (const float*)d_in[11];
    const float* Wc_h = (const float*)d_in[12];
    const float* bc_h = (const float*)d_in[13];
    const float* Wl_h = (const float*)d_in[14];
    const float* bl_h = (const float*)d_in[15];
    const float* W_lin = (const float*)d_in[16];
    const float* b_lin = (const float*)d_in[17];

    float* out_z = (float*)d_out;
    float* out_h = out_z + (size_t)NN * DD;

    // ws layout (4B words), total ~29.8 MB (same footprint as R3)
    float* ws = (float*)d_ws;
    float*  dinv   = ws;                          // 50048
    int*    deg    = (int*)(ws + 50048);          // 50048
    int*    cur    = (int*)(ws + 100096);         // 50048
    int*    cursor = (int*)(ws + 150144);         // 64
    int*    off    = (int*)(ws + 150208);         // 50048
    int*    csr    = (int*)(ws + 200256);         // 800064
    float*  bA     = ws + 1000320;                // 256
    float*  bB     = ws + 1000576;                // 128
    ushort* WAs    = (ushort*)(ws + 1000704);     // 65536 bf16
    ushort* WBs    = (ushort*)(ws + 1033472);     // 32768 bf16
    ushort* WLs    = (ushort*)(ws + 1049856);     // 16384 bf16
    ushort* AXb    = (ushort*)(ws + 1058048);     // 6.4M bf16
    ushort* Xb     = (ushort*)(ws + 4258048);     // 6.4M bf16 (reused as hb after k_gather)
    ushort* hb     = Xb;

    k_prep<<<450, 256, 0, stream>>>(Wc_z, Wl_z, bc_z, bl_z, Wc_r, Wl_r, bc_r, bl_r,
                                    Wc_h, Wl_h, bc_h, bl_h, W_lin,
                                    WAs, WBs, WLs, bA, bB);
    k_zero_int<<<392, 256, 0, stream>>>(deg, 100160);   // deg+cur+cursor contiguous
    k_deg<<<3125, 256, 0, stream>>>(dst, deg);
    k_alloc<<<196, 256, 0, stream>>>(deg, off, cursor, dinv);
    k_fill<<<3125, 256, 0, stream>>>(src, dst, off, cur, csr);
    k_cvt<<<6250, 256, 0, stream>>>(X, Xb, 1600000);
    k_gather<<<12500, 256, 0, stream>>>(Xb, X, csr, off, deg, dinv, AXb);
    k_cvt<<<6250, 256, 0, stream>>>(h, hb, 1600000);    // hb overwrites Xb (dead after k_gather)
    k_fused<<<782, 256, 0, stream>>>(AXb, hb, h, WAs, WBs, WLs, bA, bB, b_lin, out_z, out_h);
}

// Round 5
// 350.779 us; speedup vs baseline: 6.8131x; 1.0436x over previous
//
#include <hip/hip_runtime.h>
#include <math.h>

#define NN 50000
#define DD 128
#define EE 800000

typedef __attribute__((ext_vector_type(8))) short short8;
typedef __attribute__((ext_vector_type(4))) float f32x4;

__device__ __forceinline__ ushort f2bf(float f) {
    union { float f; unsigned u; } v; v.f = f;
    unsigned r = v.u + 0x7FFF + ((v.u >> 16) & 1);   // RNE
    return (ushort)(r >> 16);
}

// ---------------- X->bf16 convert fused with degree count ----------------
__global__ void k_cvt_deg(const float* __restrict__ X, ushort* __restrict__ Xb,
                          const int* __restrict__ dste, int* __restrict__ deg) {
    int i = blockIdx.x * 256 + threadIdx.x;      // grid = exactly 1.6M = NN*DD/4
    float4 v = ((const float4*)X)[i];
    ushort4 u;
    u.x = f2bf(v.x); u.y = f2bf(v.y); u.z = f2bf(v.z); u.w = f2bf(v.w);
    ((ushort4*)Xb)[i] = u;
    if (i < EE) atomicAdd(&deg[dste[i]], 1);
}

__global__ void k_alloc(const int* __restrict__ deg, int* __restrict__ off,
                        int* __restrict__ cursor, float* __restrict__ dinv) {
    int n = blockIdx.x * 256 + threadIdx.x;
    int lane = threadIdx.x & 63;
    int d = (n < NN) ? deg[n] : 0;
    int x = d;
    #pragma unroll
    for (int o = 1; o < 64; o <<= 1) {
        int y = __shfl_up(x, o);
        if (lane >= o) x += y;
    }
    int total = __shfl(x, 63);
    int base = 0;
    if (lane == 0) base = atomicAdd(cursor, total);
    base = __shfl(base, 0);
    if (n < NN) {
        off[n] = base + x - d;
        dinv[n] = rsqrtf((float)d + 1.0f);
    }
}

__global__ void k_fill(const int* __restrict__ src, const int* __restrict__ dst,
                       const int* __restrict__ off, int* __restrict__ cur,
                       int* __restrict__ csr) {
    int e = blockIdx.x * 256 + threadIdx.x;
    if (e < EE) {
        int d = dst[e];
        int slot = atomicAdd(&cur[d], 1);
        csr[off[d] + slot] = src[e];
    }
}

// ---------------- gather (bf16 rows, unroll 8) ----------------
__global__ __launch_bounds__(256) void k_gather(const ushort* __restrict__ Xb,
                                                const int* __restrict__ csr,
                                                const int* __restrict__ off,
                                                const int* __restrict__ deg,
                                                const float* __restrict__ dinv,
                                                ushort* __restrict__ AXb) {
    int tid = blockIdx.x * 256 + threadIdx.x;
    int n = tid >> 6, lane = tid & 63;
    if (n >= NN) return;
    float dd = dinv[n];
    uint a = *((const uint*)(Xb + (size_t)n * 128 + lane * 2));
    float acc0 = dd * dd * __uint_as_float(a << 16);
    float acc1 = dd * dd * __uint_as_float(a & 0xffff0000u);
    int o = off[n], cnt = deg[n];
    int i = 0;
    for (; i + 8 <= cnt; i += 8) {
        int s[8];
        #pragma unroll
        for (int u = 0; u < 8; u++) s[u] = csr[o + i + u];
        uint v[8];
        #pragma unroll
        for (int u = 0; u < 8; u++) v[u] = *((const uint*)(Xb + (size_t)s[u] * 128 + lane * 2));
        float c[8];
        #pragma unroll
        for (int u = 0; u < 8; u++) c[u] = dinv[s[u]] * dd;
        #pragma unroll
        for (int u = 0; u < 8; u++) {
            acc0 += c[u] * __uint_as_float(v[u] << 16);
            acc1 += c[u] * __uint_as_float(v[u] & 0xffff0000u);
        }
    }
    for (; i < cnt; i++) {
        int s = csr[o + i];
        float c = dinv[s] * dd;
        uint v = *((const uint*)(Xb + (size_t)s * 128 + lane * 2));
        acc0 += c * __uint_as_float(v << 16);
        acc1 += c * __uint_as_float(v & 0xffff0000u);
    }
    ushort2 u2; u2.x = f2bf(acc0); u2.y = f2bf(acc1);
    *((ushort2*)(AXb + (size_t)n * 128 + lane * 2)) = u2;
}

// ---------------- weight prep: bf16, fragment-order [ks][ct][lane][8] ----------------
// element (c,k) -> slice ks=k>>5; within slice: (c>>4)*512 + (((k>>3)&3)*16 + (c&15))*8 + (k&7)
// so a wave's B-fetch for (ct,ks) is 64 lanes x 16B CONTIGUOUS (conflict-free).
__global__ void k_prep(const float* __restrict__ Wc_z, const float* __restrict__ Wl_z,
                       const float* __restrict__ bc_z, const float* __restrict__ bl_z,
                       const float* __restrict__ Wc_r, const float* __restrict__ Wl_r,
                       const float* __restrict__ bc_r, const float* __restrict__ bl_r,
                       const float* __restrict__ Wc_h, const float* __restrict__ Wl_h,
                       const float* __restrict__ bc_h, const float* __restrict__ bl_h,
                       const float* __restrict__ W_lin,
                       ushort* __restrict__ WAs, ushort* __restrict__ WBs,
                       ushort* __restrict__ WLs, float* __restrict__ bA,
                       float* __restrict__ bB) {
    int idx = blockIdx.x * 256 + threadIdx.x;
    if (idx < 65536) {
        int k = idx >> 8, c = idx & 255, cc = c & 127;   // lanes vary over c -> Wl coalesced
        const float* Wc = (c < 128) ? Wc_z : Wc_r;
        const float* Wl = (c < 128) ? Wl_z : Wl_r;
        float v;
        if (k < 128) {
            float s = 0.f;
            for (int j = 0; j < 128; j++) s += Wc[k * 128 + j] * Wl[j * 128 + cc];
            v = s;
        } else {
            v = Wl[k * 128 + cc];
        }
        WAs[(k >> 5) * 8192 + (c >> 4) * 512 + (((k >> 3) & 3) * 16 + (c & 15)) * 8 + (k & 7)] = f2bf(v);
    } else if (idx < 98304) {
        int i2 = idx - 65536;
        int k = i2 >> 7, c = i2 & 127;
        float v;
        if (k < 128) {
            float s = 0.f;
            for (int j = 0; j < 128; j++) s += Wc_h[k * 128 + j] * Wl_h[j * 128 + c];
            v = s;
        } else {
            v = Wl_h[k * 128 + c];
        }
        WBs[(k >> 5) * 4096 + (c >> 4) * 512 + (((k >> 3) & 3) * 16 + (c & 15)) * 8 + (k & 7)] = f2bf(v);
    } else if (idx < 114688) {
        int i3 = idx - 98304;
        int k = i3 >> 7, c = i3 & 127;
        WLs[(k >> 5) * 4096 + (c >> 4) * 512 + (((k >> 3) & 3) * 16 + (c & 15)) * 8 + (k & 7)] = f2bf(W_lin[k * 128 + c]);
    } else if (idx < 114944) {
        int c = idx - 114688, cc = c & 127;
        const float* bc = (c < 128) ? bc_z : bc_r;
        const float* Wl = (c < 128) ? Wl_z : Wl_r;
        const float* bl = (c < 128) ? bl_z : bl_r;
        float s = bl[cc];
        for (int j = 0; j < 128; j++) s += bc[j] * Wl[j * 128 + cc];
        bA[c] = s;
    } else if (idx < 115072) {
        int c = idx - 114944;
        float s = bl_h[c];
        for (int j = 0; j < 128; j++) s += bc_h[j] * Wl_h[j * 128 + c];
        bB[c] = s;
    }
}

// ---------------- fused MFMA kernel ----------------
__global__ __launch_bounds__(256) void k_fused(const ushort* __restrict__ AXb,
                                               const float* __restrict__ h,
                                               const ushort* __restrict__ WAs,
                                               const ushort* __restrict__ WBs,
                                               const ushort* __restrict__ WLs,
                                               const float* __restrict__ bA,
                                               const float* __restrict__ bB,
                                               const float* __restrict__ b_lin,
                                               float* __restrict__ out_z,
                                               float* __restrict__ out_h) {
    __shared__ uint4 WbufV[2][1024];                 // 2 x 16 KB weight slices
    __shared__ __align__(16) ushort hRbuf[8192];     // 16 KB: [64 rows][128] bf16, XOR-swizzled

    const int tid = threadIdx.x;
    const int row0 = blockIdx.x * 64;
    const int lane = tid & 63, w = tid >> 6;
    const int tx = lane & 15, g = lane >> 4;
    const int arow = w * 16 + tx;          // A-operand row (this lane)
    const int gar = row0 + arow;
    const int drow = w * 16 + g * 4;       // D rows = drow + r
    const int aswz = (arow & 7) << 4;

    // ---- A-fragments: AX from bf16 global, h converted inline from f32 ----
    short8 z8 = {0, 0, 0, 0, 0, 0, 0, 0};
    short8 axf[4], hf[4];
    bool av = (gar < NN);
    #pragma unroll
    for (int ks = 0; ks < 4; ks++)
        axf[ks] = av ? *((const short8*)(AXb + (size_t)gar * 128 + ks * 32 + g * 8)) : z8;
    {
        const float4* hp = (const float4*)(h + (size_t)gar * 128);
        #pragma unroll
        for (int ks = 0; ks < 4; ks++) {
            if (av) {
                float4 u0 = hp[ks * 8 + g * 2];
                float4 u1 = hp[ks * 8 + g * 2 + 1];
                short8 t;
                t[0] = (short)f2bf(u0.x); t[1] = (short)f2bf(u0.y);
                t[2] = (short)f2bf(u0.z); t[3] = (short)f2bf(u0.w);
                t[4] = (short)f2bf(u1.x); t[5] = (short)f2bf(u1.y);
                t[6] = (short)f2bf(u1.z); t[7] = (short)f2bf(u1.w);
                hf[ks] = t;
            } else hf[ks] = z8;
        }
    }

    uint4 sr[4];
    const uint4* gwA = (const uint4*)WAs;

    // ================= phase A: [Z|R] = sigmoid([AX|h] @ WA + bA) =================
    #pragma unroll
    for (int j = 0; j < 4; j++) sr[j] = gwA[j * 256 + tid];
    #pragma unroll
    for (int j = 0; j < 4; j++) WbufV[0][j * 256 + tid] = sr[j];
    #pragma unroll
    for (int j = 0; j < 4; j++) sr[j] = gwA[1024 + j * 256 + tid];
    __syncthreads();

    f32x4 accA[16];
    #pragma unroll
    for (int ct = 0; ct < 16; ct++) accA[ct] = (f32x4){0.f, 0.f, 0.f, 0.f};

    #pragma unroll
    for (int ks = 0; ks < 8; ks++) {
        const int cur = ks & 1, nxt = cur ^ 1;
        if (ks < 7) {
            #pragma unroll
            for (int j = 0; j < 4; j++) WbufV[nxt][j * 256 + tid] = sr[j];
        }
        if (ks < 6) {
            #pragma unroll
            for (int j = 0; j < 4; j++) sr[j] = gwA[(ks + 2) * 1024 + j * 256 + tid];
        }
        const ushort* wbp = (const ushort*)WbufV[cur];
        short8 a = (ks < 4) ? axf[ks] : hf[ks - 4];
        #pragma unroll
        for (int ct = 0; ct < 16; ct++) {
            short8 b = *((const short8*)(wbp + ct * 512 + lane * 8));
            accA[ct] = __builtin_amdgcn_mfma_f32_16x16x32_bf16(a, b, accA[ct], 0, 0, 0);
        }
        __syncthreads();
    }

    // epilogue A: Z kept in regs; hR -> swizzled LDS; h kept in regs
    float Zv[8][4], hv[8][4];
    #pragma unroll
    for (int ct = 0; ct < 8; ct++) {
        float bias = bA[ct * 16 + tx];
        #pragma unroll
        for (int r = 0; r < 4; r++)
            Zv[ct][r] = 1.f / (1.f + expf(-(accA[ct][r] + bias)));
    }
    #pragma unroll
    for (int ct = 0; ct < 8; ct++) {
        int cc = ct * 16 + tx;
        float bias = bA[128 + cc];
        #pragma unroll
        for (int r = 0; r < 4; r++) {
            int rr = drow + r, gr = row0 + rr;
            float hval = (gr < NN) ? h[(size_t)gr * 128 + cc] : 0.f;
            hv[ct][r] = hval;
            float R = 1.f / (1.f + expf(-(accA[8 + ct][r] + bias)));
            *((ushort*)((char*)hRbuf + rr * 256 + ((cc * 2) ^ ((rr & 7) << 4)))) = f2bf(hval * R);
        }
    }

    // ================= phase B: H~ = tanh([AX|hR] @ WB + bB) =================
    const uint4* gwB = (const uint4*)WBs;
    #pragma unroll
    for (int j = 0; j < 2; j++) sr[j] = gwB[j * 256 + tid];
    #pragma unroll
    for (int j = 0; j < 2; j++) WbufV[0][j * 256 + tid] = sr[j];
    #pragma unroll
    for (int j = 0; j < 2; j++) sr[j] = gwB[512 + j * 256 + tid];
    __syncthreads();   // also orders hRbuf writes vs phase-B reads

    f32x4 accB[8];
    #pragma unroll
    for (int ct = 0; ct < 8; ct++) accB[ct] = (f32x4){0.f, 0.f, 0.f, 0.f};

    #pragma unroll
    for (int ks = 0; ks < 8; ks++) {
        const int cur = ks & 1, nxt = cur ^ 1;
        if (ks < 7) {
            #pragma unroll
            for (int j = 0; j < 2; j++) WbufV[nxt][j * 256 + tid] = sr[j];
        }
        if (ks < 6) {
            #pragma unroll
            for (int j = 0; j < 2; j++) sr[j] = gwB[(ks + 2) * 512 + j * 256 + tid];
        }
        const ushort* wbp = (const ushort*)WbufV[cur];
        short8 a;
        if (ks < 4) {
            a = axf[ks];
        } else {
            int kk = ks - 4;
            a = *((const short8*)((const char*)hRbuf + arow * 256 + ((kk * 64 + g * 16) ^ aswz)));
        }
        #pragma unroll
        for (int ct = 0; ct < 8; ct++) {
            short8 b = *((const short8*)(wbp + ct * 512 + lane * 8));
            accB[ct] = __builtin_amdgcn_mfma_f32_16x16x32_bf16(a, b, accB[ct], 0, 0, 0);
        }
        __syncthreads();
    }

    // epilogue B: h0 -> out_h; relu(h0) -> hRbuf
    #pragma unroll
    for (int ct = 0; ct < 8; ct++) {
        int cc = ct * 16 + tx;
        float bias = bB[cc];
        #pragma unroll
        for (int r = 0; r < 4; r++) {
            int rr = drow + r, gr = row0 + rr;
            float gv = accB[ct][r] + bias;
            float H = tanhf(gv);
            float Z = Zv[ct][r];
            float h0 = Z * hv[ct][r] + (1.f - Z) * H;
            if (gr < NN) out_h[(size_t)gr * 128 + cc] = h0;
            *((ushort*)((char*)hRbuf + rr * 256 + ((cc * 2) ^ ((rr & 7) << 4)))) = f2bf(fmaxf(h0, 0.f));
        }
    }

    // ================= phase C: z_out = relu(h0) @ WL + b_lin =================
    const uint4* gwL = (const uint4*)WLs;
    #pragma unroll
    for (int j = 0; j < 2; j++) sr[j] = gwL[j * 256 + tid];
    #pragma unroll
    for (int j = 0; j < 2; j++) WbufV[0][j * 256 + tid] = sr[j];
    #pragma unroll
    for (int j = 0; j < 2; j++) sr[j] = gwL[512 + j * 256 + tid];
    __syncthreads();   // orders relu writes vs phase-C reads

    f32x4 accC[8];
    #pragma unroll
    for (int ct = 0; ct < 8; ct++) accC[ct] = (f32x4){0.f, 0.f, 0.f, 0.f};

    #pragma unroll
    for (int ks = 0; ks < 4; ks++) {
        const int cur = ks & 1, nxt = cur ^ 1;
        if (ks < 3) {
            #pragma unroll
            for (int j = 0; j < 2; j++) WbufV[nxt][j * 256 + tid] = sr[j];
        }
        if (ks < 2) {
            #pragma unroll
            for (int j = 0; j < 2; j++) sr[j] = gwL[(ks + 2) * 512 + j * 256 + tid];
        }
        const ushort* wbp = (const ushort*)WbufV[cur];
        short8 a = *((const short8*)((const char*)hRbuf + arow * 256 + ((ks * 64 + g * 16) ^ aswz)));
        #pragma unroll
        for (int ct = 0; ct < 8; ct++) {
            short8 b = *((const short8*)(wbp + ct * 512 + lane * 8));
            accC[ct] = __builtin_amdgcn_mfma_f32_16x16x32_bf16(a, b, accC[ct], 0, 0, 0);
        }
        __syncthreads();
    }

    #pragma unroll
    for (int ct = 0; ct < 8; ct++) {
        int cc = ct * 16 + tx;
        float bias = b_lin[cc];
        #pragma unroll
        for (int r = 0; r < 4; r++) {
            int gr = row0 + drow + r;
            if (gr < NN) out_z[(size_t)gr * 128 + cc] = accC[ct][r] + bias;
        }
    }
}

// ---------------- launch ----------------

extern "C" void kernel_launch(void* const* d_in, const int* in_sizes, int n_in,
                              void* d_out, int out_size, void* d_ws, size_t ws_size,
                              hipStream_t stream) {
    const float* X    = (const float*)d_in[0];
    const int*   src  = (const int*)d_in[1];
    const int*   dst  = (const int*)d_in[2];
    const float* h    = (const float*)d_in[3];
    const float* Wc_z = (const float*)d_in[4];
    const float* bc_z = (const float*)d_in[5];
    const float* Wl_z = (const float*)d_in[6];
    const float* bl_z = (const float*)d_in[7];
    const float* Wc_r = (const float*)d_in[8];
    const float* bc_r = (const float*)d_in[9];
    const float* Wl_r = (const float*)d_in[10];
    const float* bl_r = (const float*)d_in[11];
    const float* Wc_h = (const float*)d_in[12];
    const float* bc_h = (const float*)d_in[13];
    const float* Wl_h = (const float*)d_in[14];
    const float* bl_h = (const float*)d_in[15];
    const float* W_lin = (const float*)d_in[16];
    const float* b_lin = (const float*)d_in[17];

    float* out_z = (float*)d_out;
    float* out_h = out_z + (size_t)NN * DD;

    // ws layout (4B words)
    float* ws = (float*)d_ws;
    float*  dinv   = ws;                          // 50048
    int*    deg    = (int*)(ws + 50048);          // 50048
    int*    cur    = (int*)(ws + 100096);         // 50048
    int*    cursor = (int*)(ws + 150144);         // 64
    int*    off    = (int*)(ws + 150208);         // 50048
    int*    csr    = (int*)(ws + 200256);         // 800064
    float*  bA     = ws + 1000320;                // 256
    float*  bB     = ws + 1000576;                // 128
    ushort* WAs    = (ushort*)(ws + 1000704);     // 65536 bf16
    ushort* WBs    = (ushort*)(ws + 1033472);     // 32768 bf16
    ushort* WLs    = (ushort*)(ws + 1049856);     // 16384 bf16
    ushort* AXb    = (ushort*)(ws + 1058048);     // 6.4M bf16
    ushort* Xb     = (ushort*)(ws + 4258048);     // 6.4M bf16

    hipMemsetAsync(deg, 0, 100160 * sizeof(int), stream);   // deg + cur + cursor
    k_prep<<<450, 256, 0, stream>>>(Wc_z, Wl_z, bc_z, bl_z, Wc_r, Wl_r, bc_r, bl_r,
                                    Wc_h, Wl_h, bc_h, bl_h, W_lin,
                                    WAs, WBs, WLs, bA, bB);
    k_cvt_deg<<<6250, 256, 0, stream>>>(X, Xb, dst, deg);
    k_alloc<<<196, 256, 0, stream>>>(deg, off, cursor, dinv);
    k_fill<<<3125, 256, 0, stream>>>(src, dst, off, cur, csr);
    k_gather<<<12500, 256, 0, stream>>>(Xb, csr, off, deg, dinv, AXb);
    k_fused<<<782, 256, 0, stream>>>(AXb, h, WAs, WBs, WLs, bA, bB, b_lin, out_z, out_h);
}

// Round 7
// 350.009 us; speedup vs baseline: 6.8281x; 1.0022x over previous
//
#include <hip/hip_runtime.h>
#include <math.h>

#define NN 50000
#define DD 128
#define EE 800000

typedef __attribute__((ext_vector_type(8))) short short8;
typedef __attribute__((ext_vector_type(4))) float f32x4;

__device__ __forceinline__ ushort f2bf(float f) {
    union { float f; unsigned u; } v; v.f = f;
    unsigned r = v.u + 0x7FFF + ((v.u >> 16) & 1);   // RNE
    return (ushort)(r >> 16);
}

// ---------------- X->bf16 convert + degree count + weight prep (fused) ----------------
// blocks [0,6250): convert X (1.6M float4) and count degrees (first 800k threads)
// blocks [6250,6700): weight prep (115072 work items)
__global__ void k_cvtprep(const float* __restrict__ X, ushort* __restrict__ Xb,
                          const int* __restrict__ dste, int* __restrict__ deg,
                          const float* __restrict__ Wc_z, const float* __restrict__ Wl_z,
                          const float* __restrict__ bc_z, const float* __restrict__ bl_z,
                          const float* __restrict__ Wc_r, const float* __restrict__ Wl_r,
                          const float* __restrict__ bc_r, const float* __restrict__ bl_r,
                          const float* __restrict__ Wc_h, const float* __restrict__ Wl_h,
                          const float* __restrict__ bc_h, const float* __restrict__ bl_h,
                          const float* __restrict__ W_lin,
                          ushort* __restrict__ WAs, ushort* __restrict__ WBs,
                          ushort* __restrict__ WLs, float* __restrict__ bA,
                          float* __restrict__ bB) {
    if (blockIdx.x < 6250) {
        int i = blockIdx.x * 256 + threadIdx.x;      // exactly 1.6M = NN*DD/4
        float4 v = ((const float4*)X)[i];
        ushort4 u;
        u.x = f2bf(v.x); u.y = f2bf(v.y); u.z = f2bf(v.z); u.w = f2bf(v.w);
        ((ushort4*)Xb)[i] = u;
        if (i < EE) atomicAdd(&deg[dste[i]], 1);
        return;
    }
    int idx = (blockIdx.x - 6250) * 256 + threadIdx.x;
    if (idx < 65536) {
        int k = idx >> 8, c = idx & 255, cc = c & 127;   // lanes vary over c -> Wl coalesced
        const float* Wc = (c < 128) ? Wc_z : Wc_r;
        const float* Wl = (c < 128) ? Wl_z : Wl_r;
        float v;
        if (k < 128) {
            float s = 0.f;
            for (int j = 0; j < 128; j++) s += Wc[k * 128 + j] * Wl[j * 128 + cc];
            v = s;
        } else {
            v = Wl[k * 128 + cc];
        }
        WAs[(k >> 5) * 8192 + (c >> 4) * 512 + (((k >> 3) & 3) * 16 + (c & 15)) * 8 + (k & 7)] = f2bf(v);
    } else if (idx < 98304) {
        int i2 = idx - 65536;
        int k = i2 >> 7, c = i2 & 127;
        float v;
        if (k < 128) {
            float s = 0.f;
            for (int j = 0; j < 128; j++) s += Wc_h[k * 128 + j] * Wl_h[j * 128 + c];
            v = s;
        } else {
            v = Wl_h[k * 128 + c];
        }
        WBs[(k >> 5) * 4096 + (c >> 4) * 512 + (((k >> 3) & 3) * 16 + (c & 15)) * 8 + (k & 7)] = f2bf(v);
    } else if (idx < 114688) {
        int i3 = idx - 98304;
        int k = i3 >> 7, c = i3 & 127;
        WLs[(k >> 5) * 4096 + (c >> 4) * 512 + (((k >> 3) & 3) * 16 + (c & 15)) * 8 + (k & 7)] = f2bf(W_lin[k * 128 + c]);
    } else if (idx < 114944) {
        int c = idx - 114688, cc = c & 127;
        const float* bc = (c < 128) ? bc_z : bc_r;
        const float* Wl = (c < 128) ? Wl_z : Wl_r;
        const float* bl = (c < 128) ? bl_z : bl_r;
        float s = bl[cc];
        for (int j = 0; j < 128; j++) s += bc[j] * Wl[j * 128 + cc];
        bA[c] = s;
    } else if (idx < 115072) {
        int c = idx - 114944;
        float s = bl_h[c];
        for (int j = 0; j < 128; j++) s += bc_h[j] * Wl_h[j * 128 + c];
        bB[c] = s;
    }
}

__global__ void k_alloc(const int* __restrict__ deg, int* __restrict__ off,
                        int* __restrict__ cursor, float* __restrict__ dinv) {
    int n = blockIdx.x * 256 + threadIdx.x;
    int lane = threadIdx.x & 63;
    int d = (n < NN) ? deg[n] : 0;
    int x = d;
    #pragma unroll
    for (int o = 1; o < 64; o <<= 1) {
        int y = __shfl_up(x, o);
        if (lane >= o) x += y;
    }
    int total = __shfl(x, 63);
    int base = 0;
    if (lane == 0) base = atomicAdd(cursor, total);
    base = __shfl(base, 0);
    if (n < NN) {
        off[n] = base + x - d;
        dinv[n] = rsqrtf((float)d + 1.0f);
    }
}

__global__ void k_fill(const int* __restrict__ src, const int* __restrict__ dst,
                       const int* __restrict__ off, int* __restrict__ cur,
                       int* __restrict__ csr) {
    int e = blockIdx.x * 256 + threadIdx.x;
    if (e < EE) {
        int d = dst[e];
        int slot = atomicAdd(&cur[d], 1);
        csr[off[d] + slot] = src[e];
    }
}

// ---------------- gather (bf16 rows, unroll 8, scalarized CSR reads) ----------------
__global__ __launch_bounds__(256) void k_gather(const ushort* __restrict__ Xb,
                                                const int* __restrict__ csr,
                                                const int* __restrict__ off,
                                                const int* __restrict__ deg,
                                                const float* __restrict__ dinv,
                                                ushort* __restrict__ AXb) {
    int tid = blockIdx.x * 256 + threadIdx.x;
    int n = tid >> 6, lane = tid & 63;
    if (n >= NN) return;
    // o/cnt are wave-uniform: scalarize so csr/dinv index loads go down the s_load pipe
    int o   = __builtin_amdgcn_readfirstlane(off[n]);
    int cnt = __builtin_amdgcn_readfirstlane(deg[n]);
    float dd = dinv[n];
    uint a = *((const uint*)(Xb + (size_t)n * 128 + lane * 2));
    float acc0 = dd * dd * __uint_as_float(a << 16);
    float acc1 = dd * dd * __uint_as_float(a & 0xffff0000u);
    int i = 0;
    for (; i + 8 <= cnt; i += 8) {
        int s[8];
        #pragma unroll
        for (int u = 0; u < 8; u++) s[u] = csr[o + i + u];
        uint v[8];
        #pragma unroll
        for (int u = 0; u < 8; u++) v[u] = *((const uint*)(Xb + (size_t)s[u] * 128 + lane * 2));
        float c[8];
        #pragma unroll
        for (int u = 0; u < 8; u++) c[u] = dinv[s[u]] * dd;
        #pragma unroll
        for (int u = 0; u < 8; u++) {
            acc0 += c[u] * __uint_as_float(v[u] << 16);
            acc1 += c[u] * __uint_as_float(v[u] & 0xffff0000u);
        }
    }
    for (; i < cnt; i++) {
        int s = csr[o + i];
        float c = dinv[s] * dd;
        uint v = *((const uint*)(Xb + (size_t)s * 128 + lane * 2));
        acc0 += c * __uint_as_float(v << 16);
        acc1 += c * __uint_as_float(v & 0xffff0000u);
    }
    ushort2 u2; u2.x = f2bf(acc0); u2.y = f2bf(acc1);
    *((ushort2*)(AXb + (size_t)n * 128 + lane * 2)) = u2;
}

// ---------------- fused MFMA kernel: 128 rows/block, 2 row-tiles per wave ----------------
// wave w owns rows [w*32, w*32+32) as two 16-row tiles; B-fragment reused across tiles.
__global__ __launch_bounds__(256, 2) void k_fused(const ushort* __restrict__ AXb,
                                                  const float* __restrict__ h,
                                                  const ushort* __restrict__ WAs,
                                                  const ushort* __restrict__ WBs,
                                                  const ushort* __restrict__ WLs,
                                                  const float* __restrict__ bA,
                                                  const float* __restrict__ bB,
                                                  const float* __restrict__ b_lin,
                                                  float* __restrict__ out_z,
                                                  float* __restrict__ out_h) {
    __shared__ uint4 WbufV[2][1024];                  // 2 x 16 KB weight slices
    __shared__ __align__(16) ushort hRbuf[16384];     // 32 KB: [128 rows][128] bf16, XOR-swizzled

    const int tid = threadIdx.x;
    const int row0 = blockIdx.x * 128;
    const int lane = tid & 63, w = tid >> 6;
    const int tx = lane & 15, g = lane >> 4;

    int arow[2], gar[2], aswz[2];
    bool av[2];
    #pragma unroll
    for (int t = 0; t < 2; t++) {
        arow[t] = w * 32 + t * 16 + tx;
        gar[t]  = row0 + arow[t];
        av[t]   = gar[t] < NN;
        aswz[t] = (arow[t] & 7) << 4;
    }
    const int drow0 = w * 32 + g * 4;   // tile t adds t*16; D rows = drow0 + t*16 + r

    // ---- A-fragments: AX from bf16 global, h converted inline from f32 ----
    short8 z8 = {0, 0, 0, 0, 0, 0, 0, 0};
    short8 axf[2][4], hf[2][4];
    #pragma unroll
    for (int t = 0; t < 2; t++) {
        #pragma unroll
        for (int ks = 0; ks < 4; ks++)
            axf[t][ks] = av[t] ? *((const short8*)(AXb + (size_t)gar[t] * 128 + ks * 32 + g * 8)) : z8;
        const float4* hp = (const float4*)(h + (size_t)gar[t] * 128);
        #pragma unroll
        for (int ks = 0; ks < 4; ks++) {
            if (av[t]) {
                float4 u0 = hp[ks * 8 + g * 2];
                float4 u1 = hp[ks * 8 + g * 2 + 1];
                short8 tt;
                tt[0] = (short)f2bf(u0.x); tt[1] = (short)f2bf(u0.y);
                tt[2] = (short)f2bf(u0.z); tt[3] = (short)f2bf(u0.w);
                tt[4] = (short)f2bf(u1.x); tt[5] = (short)f2bf(u1.y);
                tt[6] = (short)f2bf(u1.z); tt[7] = (short)f2bf(u1.w);
                hf[t][ks] = tt;
            } else hf[t][ks] = z8;
        }
    }

    uint4 sr[4];
    const uint4* gwA = (const uint4*)WAs;

    // ================= phase A: [Z|R] = sigmoid([AX|h] @ WA + bA) =================
    #pragma unroll
    for (int j = 0; j < 4; j++) sr[j] = gwA[j * 256 + tid];
    #pragma unroll
    for (int j = 0; j < 4; j++) WbufV[0][j * 256 + tid] = sr[j];
    #pragma unroll
    for (int j = 0; j < 4; j++) sr[j] = gwA[1024 + j * 256 + tid];
    __syncthreads();

    f32x4 accA[2][16];
    #pragma unroll
    for (int t = 0; t < 2; t++)
        #pragma unroll
        for (int ct = 0; ct < 16; ct++) accA[t][ct] = (f32x4){0.f, 0.f, 0.f, 0.f};

    #pragma unroll
    for (int ks = 0; ks < 8; ks++) {
        const int cur = ks & 1, nxt = cur ^ 1;
        if (ks < 7) {
            #pragma unroll
            for (int j = 0; j < 4; j++) WbufV[nxt][j * 256 + tid] = sr[j];
        }
        if (ks < 6) {
            #pragma unroll
            for (int j = 0; j < 4; j++) sr[j] = gwA[(ks + 2) * 1024 + j * 256 + tid];
        }
        const ushort* wbp = (const ushort*)WbufV[cur];
        short8 a0 = (ks < 4) ? axf[0][ks] : hf[0][ks - 4];
        short8 a1 = (ks < 4) ? axf[1][ks] : hf[1][ks - 4];
        #pragma unroll
        for (int ct = 0; ct < 16; ct++) {
            short8 b = *((const short8*)(wbp + ct * 512 + lane * 8));
            accA[0][ct] = __builtin_amdgcn_mfma_f32_16x16x32_bf16(a0, b, accA[0][ct], 0, 0, 0);
            accA[1][ct] = __builtin_amdgcn_mfma_f32_16x16x32_bf16(a1, b, accA[1][ct], 0, 0, 0);
        }
        __syncthreads();
    }

    // epilogue A: Z kept in regs; hR -> swizzled LDS (h re-read later in epilogue B)
    float Zv[2][8][4];
    #pragma unroll
    for (int t = 0; t < 2; t++)
        #pragma unroll
        for (int ct = 0; ct < 8; ct++) {
            float bias = bA[ct * 16 + tx];
            #pragma unroll
            for (int r = 0; r < 4; r++)
                Zv[t][ct][r] = 1.f / (1.f + expf(-(accA[t][ct][r] + bias)));
        }
    #pragma unroll
    for (int t = 0; t < 2; t++)
        #pragma unroll
        for (int ct = 0; ct < 8; ct++) {
            int cc = ct * 16 + tx;
            float bias = bA[128 + cc];
            #pragma unroll
            for (int r = 0; r < 4; r++) {
                int rr = drow0 + t * 16 + r, gr = row0 + rr;
                float hval = (gr < NN) ? h[(size_t)gr * 128 + cc] : 0.f;
                float R = 1.f / (1.f + expf(-(accA[t][8 + ct][r] + bias)));
                *((ushort*)((char*)hRbuf + rr * 256 + ((cc * 2) ^ ((rr & 7) << 4)))) = f2bf(hval * R);
            }
        }

    // ================= phase B: H~ = tanh([AX|hR] @ WB + bB) =================
    const uint4* gwB = (const uint4*)WBs;
    #pragma unroll
    for (int j = 0; j < 2; j++) sr[j] = gwB[j * 256 + tid];
    #pragma unroll
    for (int j = 0; j < 2; j++) WbufV[0][j * 256 + tid] = sr[j];
    #pragma unroll
    for (int j = 0; j < 2; j++) sr[j] = gwB[512 + j * 256 + tid];
    __syncthreads();   // also orders hRbuf writes vs phase-B reads

    f32x4 accB[2][8];
    #pragma unroll
    for (int t = 0; t < 2; t++)
        #pragma unroll
        for (int ct = 0; ct < 8; ct++) accB[t][ct] = (f32x4){0.f, 0.f, 0.f, 0.f};

    #pragma unroll
    for (int ks = 0; ks < 8; ks++) {
        const int cur = ks & 1, nxt = cur ^ 1;
        if (ks < 7) {
            #pragma unroll
            for (int j = 0; j < 2; j++) WbufV[nxt][j * 256 + tid] = sr[j];
        }
        if (ks < 6) {
            #pragma unroll
            for (int j = 0; j < 2; j++) sr[j] = gwB[(ks + 2) * 512 + j * 256 + tid];
        }
        const ushort* wbp = (const ushort*)WbufV[cur];
        short8 a0, a1;
        if (ks < 4) {
            a0 = axf[0][ks]; a1 = axf[1][ks];
        } else {
            int kk = ks - 4;
            a0 = *((const short8*)((const char*)hRbuf + arow[0] * 256 + ((kk * 64 + g * 16) ^ aswz[0])));
            a1 = *((const short8*)((const char*)hRbuf + arow[1] * 256 + ((kk * 64 + g * 16) ^ aswz[1])));
        }
        #pragma unroll
        for (int ct = 0; ct < 8; ct++) {
            short8 b = *((const short8*)(wbp + ct * 512 + lane * 8));
            accB[0][ct] = __builtin_amdgcn_mfma_f32_16x16x32_bf16(a0, b, accB[0][ct], 0, 0, 0);
            accB[1][ct] = __builtin_amdgcn_mfma_f32_16x16x32_bf16(a1, b, accB[1][ct], 0, 0, 0);
        }
        __syncthreads();
    }

    // epilogue B: h0 -> out_h; relu(h0) -> hRbuf (h re-read from L2)
    #pragma unroll
    for (int t = 0; t < 2; t++)
        #pragma unroll
        for (int ct = 0; ct < 8; ct++) {
            int cc = ct * 16 + tx;
            float bias = bB[cc];
            #pragma unroll
            for (int r = 0; r < 4; r++) {
                int rr = drow0 + t * 16 + r, gr = row0 + rr;
                float hval = (gr < NN) ? h[(size_t)gr * 128 + cc] : 0.f;
                float gv = accB[t][ct][r] + bias;
                float H = tanhf(gv);
                float Z = Zv[t][ct][r];
                float h0 = Z * hval + (1.f - Z) * H;
                if (gr < NN) out_h[(size_t)gr * 128 + cc] = h0;
                *((ushort*)((char*)hRbuf + rr * 256 + ((cc * 2) ^ ((rr & 7) << 4)))) = f2bf(fmaxf(h0, 0.f));
            }
        }

    // ================= phase C: z_out = relu(h0) @ WL + b_lin =================
    const uint4* gwL = (const uint4*)WLs;
    #pragma unroll
    for (int j = 0; j < 2; j++) sr[j] = gwL[j * 256 + tid];
    #pragma unroll
    for (int j = 0; j < 2; j++) WbufV[0][j * 256 + tid] = sr[j];
    #pragma unroll
    for (int j = 0; j < 2; j++) sr[j] = gwL[512 + j * 256 + tid];
    __syncthreads();   // orders relu writes vs phase-C reads

    f32x4 accC[2][8];
    #pragma unroll
    for (int t = 0; t < 2; t++)
        #pragma unroll
        for (int ct = 0; ct < 8; ct++) accC[t][ct] = (f32x4){0.f, 0.f, 0.f, 0.f};

    #pragma unroll
    for (int ks = 0; ks < 4; ks++) {
        const int cur = ks & 1, nxt = cur ^ 1;
        if (ks < 3) {
            #pragma unroll
            for (int j = 0; j < 2; j++) WbufV[nxt][j * 256 + tid] = sr[j];
        }
        if (ks < 2) {
            #pragma unroll
            for (int j = 0; j < 2; j++) sr[j] = gwL[(ks + 2) * 512 + j * 256 + tid];
        }
        const ushort* wbp = (const ushort*)WbufV[cur];
        short8 a0 = *((const short8*)((const char*)hRbuf + arow[0] * 256 + ((ks * 64 + g * 16) ^ aswz[0])));
        short8 a1 = *((const short8*)((const char*)hRbuf + arow[1] * 256 + ((ks * 64 + g * 16) ^ aswz[1])));
        #pragma unroll
        for (int ct = 0; ct < 8; ct++) {
            short8 b = *((const short8*)(wbp + ct * 512 + lane * 8));
            accC[0][ct] = __builtin_amdgcn_mfma_f32_16x16x32_bf16(a0, b, accC[0][ct], 0, 0, 0);
            accC[1][ct] = __builtin_amdgcn_mfma_f32_16x16x32_bf16(a1, b, accC[1][ct], 0, 0, 0);
        }
        __syncthreads();
    }

    #pragma unroll
    for (int t = 0; t < 2; t++)
        #pragma unroll
        for (int ct = 0; ct < 8; ct++) {
            int cc = ct * 16 + tx;
            float bias = b_lin[cc];
            #pragma unroll
            for (int r = 0; r < 4; r++) {
                int gr = row0 + drow0 + t * 16 + r;
                if (gr < NN) out_z[(size_t)gr * 128 + cc] = accC[t][ct][r] + bias;
            }
        }
}

// ---------------- launch ----------------

extern "C" void kernel_launch(void* const* d_in, const int* in_sizes, int n_in,
                              void* d_out, int out_size, void* d_ws, size_t ws_size,
                              hipStream_t stream) {
    const float* X    = (const float*)d_in[0];
    const int*   src  = (const int*)d_in[1];
    const int*   dst  = (const int*)d_in[2];
    const float* h    = (const float*)d_in[3];
    const float* Wc_z = (const float*)d_in[4];
    const float* bc_z = (const float*)d_in[5];
    const float* Wl_z = (const float*)d_in[6];
    const float* bl_z = (const float*)d_in[7];
    const float* Wc_r = (const float*)d_in[8];
    const float* bc_r = (const float*)d_in[9];
    const float* Wl_r = (const float*)d_in[10];
    const float* bl_r = (const float*)d_in[11];
    const float* Wc_h = (const float*)d_in[12];
    const float* bc_h = (const float*)d_in[13];
    const float* Wl_h = (const float*)d_in[14];
    const float* bl_h = (const float*)d_in[15];
    const float* W_lin = (const float*)d_in[16];
    const float* b_lin = (const float*)d_in[17];

    float* out_z = (float*)d_out;
    float* out_h = out_z + (size_t)NN * DD;

    // ws layout (4B words)
    float* ws = (float*)d_ws;
    float*  dinv   = ws;                          // 50048
    int*    deg    = (int*)(ws + 50048);          // 50048
    int*    cur    = (int*)(ws + 100096);         // 50048
    int*    cursor = (int*)(ws + 150144);         // 64
    int*    off    = (int*)(ws + 150208);         // 50048
    int*    csr    = (int*)(ws + 200256);         // 800064
    float*  bA     = ws + 1000320;                // 256
    float*  bB     = ws + 1000576;                // 128
    ushort* WAs    = (ushort*)(ws + 1000704);     // 65536 bf16
    ushort* WBs    = (ushort*)(ws + 1033472);     // 32768 bf16
    ushort* WLs    = (ushort*)(ws + 1049856);     // 16384 bf16
    ushort* AXb    = (ushort*)(ws + 1058048);     // 6.4M bf16
    ushort* Xb     = (ushort*)(ws + 4258048);     // 6.4M bf16

    hipMemsetAsync(deg, 0, 100160 * sizeof(int), stream);   // deg + cur + cursor
    k_cvtprep<<<6700, 256, 0, stream>>>(X, Xb, dst, deg,
                                        Wc_z, Wl_z, bc_z, bl_z, Wc_r, Wl_r, bc_r, bl_r,
                                        Wc_h, Wl_h, bc_h, bl_h, W_lin,
                                        WAs, WBs, WLs, bA, bB);
    k_alloc<<<196, 256, 0, stream>>>(deg, off, cursor, dinv);
    k_fill<<<3125, 256, 0, stream>>>(src, dst, off, cur, csr);
    k_gather<<<12500, 256, 0, stream>>>(Xb, csr, off, deg, dinv, AXb);
    k_fused<<<391, 256, 0, stream>>>(AXb, h, WAs, WBs, WLs, bA, bB, b_lin, out_z, out_h);
}

// Round 8
// 327.260 us; speedup vs baseline: 7.3028x; 1.0695x over previous
//
#include <hip/hip_runtime.h>
#include <math.h>

#define NN 50000
#define DD 128
#define EE 800000
#define NSUB 3125   // 16-row subtiles, exact: 50000 = 16*3125

typedef __attribute__((ext_vector_type(8))) short short8;
typedef __attribute__((ext_vector_type(4))) float f32x4;

__device__ __forceinline__ ushort f2bf(float f) {
    union { float f; unsigned u; } v; v.f = f;
    unsigned r = v.u + 0x7FFF + ((v.u >> 16) & 1);   // RNE
    return (ushort)(r >> 16);
}
__device__ __forceinline__ float bf2f(ushort u) {
    return __uint_as_float(((unsigned)u) << 16);
}
__device__ __forceinline__ float sigm(float x) { return 1.f / (1.f + expf(-x)); }

// ---------------- convert X,h -> bf16 + degree count + weight prep ----------------
// blocks [0,6250): X convert (+deg atomics in first 800k threads)
// blocks [6250,12500): h convert
// blocks [12500,12950): weight prep (115072 items)
__global__ void k_cvtprep(const float* __restrict__ X, ushort* __restrict__ Xb,
                          const float* __restrict__ h, ushort* __restrict__ hb,
                          const int* __restrict__ dste, int* __restrict__ deg,
                          const float* __restrict__ Wc_z, const float* __restrict__ Wl_z,
                          const float* __restrict__ bc_z, const float* __restrict__ bl_z,
                          const float* __restrict__ Wc_r, const float* __restrict__ Wl_r,
                          const float* __restrict__ bc_r, const float* __restrict__ bl_r,
                          const float* __restrict__ Wc_h, const float* __restrict__ Wl_h,
                          const float* __restrict__ bc_h, const float* __restrict__ bl_h,
                          const float* __restrict__ W_lin,
                          ushort* __restrict__ WAs, ushort* __restrict__ WBs,
                          ushort* __restrict__ WLs, float* __restrict__ bA,
                          float* __restrict__ bB) {
    if (blockIdx.x < 6250) {
        int i = blockIdx.x * 256 + threadIdx.x;
        float4 v = ((const float4*)X)[i];
        ushort4 u;
        u.x = f2bf(v.x); u.y = f2bf(v.y); u.z = f2bf(v.z); u.w = f2bf(v.w);
        ((ushort4*)Xb)[i] = u;
        if (i < EE) atomicAdd(&deg[dste[i]], 1);
        return;
    }
    if (blockIdx.x < 12500) {
        int i = (blockIdx.x - 6250) * 256 + threadIdx.x;
        float4 v = ((const float4*)h)[i];
        ushort4 u;
        u.x = f2bf(v.x); u.y = f2bf(v.y); u.z = f2bf(v.z); u.w = f2bf(v.w);
        ((ushort4*)hb)[i] = u;
        return;
    }
    int idx = (blockIdx.x - 12500) * 256 + threadIdx.x;
    // fragment-order: [ks][ctg][lane][8], lane = ((k>>3)&3)*16 + (c&15), elem k&7
    if (idx < 65536) {
        int k = idx >> 8, c = idx & 255, cc = c & 127;
        const float* Wc = (c < 128) ? Wc_z : Wc_r;
        const float* Wl = (c < 128) ? Wl_z : Wl_r;
        float v;
        if (k < 128) {
            float s = 0.f;
            for (int j = 0; j < 128; j++) s += Wc[k * 128 + j] * Wl[j * 128 + cc];
            v = s;
        } else {
            v = Wl[k * 128 + cc];
        }
        WAs[(k >> 5) * 8192 + (c >> 4) * 512 + (((k >> 3) & 3) * 16 + (c & 15)) * 8 + (k & 7)] = f2bf(v);
    } else if (idx < 98304) {
        int i2 = idx - 65536;
        int k = i2 >> 7, c = i2 & 127;
        float v;
        if (k < 128) {
            float s = 0.f;
            for (int j = 0; j < 128; j++) s += Wc_h[k * 128 + j] * Wl_h[j * 128 + c];
            v = s;
        } else {
            v = Wl_h[k * 128 + c];
        }
        WBs[(k >> 5) * 4096 + (c >> 4) * 512 + (((k >> 3) & 3) * 16 + (c & 15)) * 8 + (k & 7)] = f2bf(v);
    } else if (idx < 114688) {
        int i3 = idx - 98304;
        int k = i3 >> 7, c = i3 & 127;
        WLs[(k >> 5) * 4096 + (c >> 4) * 512 + (((k >> 3) & 3) * 16 + (c & 15)) * 8 + (k & 7)] = f2bf(W_lin[k * 128 + c]);
    } else if (idx < 114944) {
        int c = idx - 114688, cc = c & 127;
        const float* bc = (c < 128) ? bc_z : bc_r;
        const float* Wl = (c < 128) ? Wl_z : Wl_r;
        const float* bl = (c < 128) ? bl_z : bl_r;
        float s = bl[cc];
        for (int j = 0; j < 128; j++) s += bc[j] * Wl[j * 128 + cc];
        bA[c] = s;
    } else if (idx < 115072) {
        int c = idx - 114944;
        float s = bl_h[c];
        for (int j = 0; j < 128; j++) s += bc_h[j] * Wl_h[j * 128 + c];
        bB[c] = s;
    }
}

__global__ void k_alloc(const int* __restrict__ deg, int* __restrict__ off,
                        int* __restrict__ cur, int* __restrict__ cursor,
                        float* __restrict__ dinv) {
    int n = blockIdx.x * 256 + threadIdx.x;
    int lane = threadIdx.x & 63;
    int d = (n < NN) ? deg[n] : 0;
    int x = d;
    #pragma unroll
    for (int o = 1; o < 64; o <<= 1) {
        int y = __shfl_up(x, o);
        if (lane >= o) x += y;
    }
    int total = __shfl(x, 63);
    int base = 0;
    if (lane == 0) base = atomicAdd(cursor, total);
    base = __shfl(base, 0);
    if (n < NN) {
        int o2 = base + x - d;
        off[n] = o2;
        cur[n] = o2;                  // fill cursor starts at offset
        dinv[n] = rsqrtf((float)d + 1.0f);
    }
}

__global__ void k_fill(const int* __restrict__ src, const int* __restrict__ dst,
                       int* __restrict__ cur, int* __restrict__ csr) {
    int e = blockIdx.x * 256 + threadIdx.x;
    if (e < EE) {
        int slot = atomicAdd(&cur[dst[e]], 1);
        csr[slot] = src[e];
    }
}

// ---------------- gather (bf16 rows, unroll 8) ----------------
__global__ __launch_bounds__(256) void k_gather(const ushort* __restrict__ Xb,
                                                const int* __restrict__ csr,
                                                const int* __restrict__ off,
                                                const int* __restrict__ deg,
                                                const float* __restrict__ dinv,
                                                ushort* __restrict__ AXb) {
    int tid = blockIdx.x * 256 + threadIdx.x;
    int n = tid >> 6, lane = tid & 63;
    if (n >= NN) return;
    int o   = __builtin_amdgcn_readfirstlane(off[n]);
    int cnt = __builtin_amdgcn_readfirstlane(deg[n]);
    float dd = dinv[n];
    uint a = *((const uint*)(Xb + (size_t)n * 128 + lane * 2));
    float acc0 = dd * dd * __uint_as_float(a << 16);
    float acc1 = dd * dd * __uint_as_float(a & 0xffff0000u);
    int i = 0;
    for (; i + 8 <= cnt; i += 8) {
        int s[8];
        #pragma unroll
        for (int u = 0; u < 8; u++) s[u] = csr[o + i + u];
        uint v[8];
        #pragma unroll
        for (int u = 0; u < 8; u++) v[u] = *((const uint*)(Xb + (size_t)s[u] * 128 + lane * 2));
        float c[8];
        #pragma unroll
        for (int u = 0; u < 8; u++) c[u] = dinv[s[u]] * dd;
        #pragma unroll
        for (int u = 0; u < 8; u++) {
            acc0 += c[u] * __uint_as_float(v[u] << 16);
            acc1 += c[u] * __uint_as_float(v[u] & 0xffff0000u);
        }
    }
    for (; i < cnt; i++) {
        int s = csr[o + i];
        float c = dinv[s] * dd;
        uint v = *((const uint*)(Xb + (size_t)s * 128 + lane * 2));
        acc0 += c * __uint_as_float(v << 16);
        acc1 += c * __uint_as_float(v & 0xffff0000u);
    }
    ushort2 u2; u2.x = f2bf(acc0); u2.y = f2bf(acc1);
    *((ushort2*)(AXb + (size_t)n * 128 + lane * 2)) = u2;
}

// ---------------- phase A: weight-stationary, barrier-free ----------------
// 4 waves/block; wave w owns cols [w*64, w*64+64). Waves 0,1: Z (transposed out).
// Waves 2,3: hR -> row-major bf16 via per-wave LDS transpose (no block barrier).
__global__ __launch_bounds__(256, 2) void k_gemmA(const ushort* __restrict__ AXb,
                                                  const ushort* __restrict__ hb,
                                                  const float* __restrict__ h,
                                                  const ushort* __restrict__ WAs,
                                                  const float* __restrict__ bA,
                                                  ushort* __restrict__ Zt,
                                                  ushort* __restrict__ hRb) {
    __shared__ ushort scr[4][1024];   // per-wave 16x64 bf16 transpose scratch
    const int tid = threadIdx.x, lane = tid & 63, w = tid >> 6;
    const int tx = lane & 15, g = lane >> 4;

    short8 wf[4][8];
    #pragma unroll
    for (int ct = 0; ct < 4; ct++)
        #pragma unroll
        for (int ks = 0; ks < 8; ks++)
            wf[ct][ks] = *((const short8*)(WAs + ks * 8192 + (w * 4 + ct) * 512 + lane * 8));
    float bias[4];
    #pragma unroll
    for (int ct = 0; ct < 4; ct++) bias[ct] = bA[w * 64 + ct * 16 + tx];

    for (int rs = blockIdx.x; rs < NSUB; rs += gridDim.x) {
        const int arow = rs * 16 + tx;
        short8 axf[4], hf[4];
        #pragma unroll
        for (int ks = 0; ks < 4; ks++) {
            axf[ks] = *((const short8*)(AXb + (size_t)arow * 128 + ks * 32 + g * 8));
            hf[ks]  = *((const short8*)(hb  + (size_t)arow * 128 + ks * 32 + g * 8));
        }
        f32x4 acc[4];
        #pragma unroll
        for (int ct = 0; ct < 4; ct++) acc[ct] = (f32x4){0.f, 0.f, 0.f, 0.f};
        #pragma unroll
        for (int ks = 0; ks < 4; ks++)
            #pragma unroll
            for (int ct = 0; ct < 4; ct++)
                acc[ct] = __builtin_amdgcn_mfma_f32_16x16x32_bf16(axf[ks], wf[ct][ks], acc[ct], 0, 0, 0);
        #pragma unroll
        for (int ks = 0; ks < 4; ks++)
            #pragma unroll
            for (int ct = 0; ct < 4; ct++)
                acc[ct] = __builtin_amdgcn_mfma_f32_16x16x32_bf16(hf[ks], wf[ct][4 + ks], acc[ct], 0, 0, 0);

        const int r0 = rs * 16 + g * 4;
        if (w < 2) {
            // Z: transposed layout Zt[col][row], 8B stores
            #pragma unroll
            for (int ct = 0; ct < 4; ct++) {
                int col = w * 64 + ct * 16 + tx;
                ushort4 z4;
                z4.x = f2bf(sigm(acc[ct][0] + bias[ct]));
                z4.y = f2bf(sigm(acc[ct][1] + bias[ct]));
                z4.z = f2bf(sigm(acc[ct][2] + bias[ct]));
                z4.w = f2bf(sigm(acc[ct][3] + bias[ct]));
                *((ushort4*)(Zt + (size_t)col * NN + r0)) = z4;
            }
        } else {
            // hR = h*sigmoid(R): in-wave transpose -> row-major bf16
            #pragma unroll
            for (int ct = 0; ct < 4; ct++) {
                int cl = ct * 16 + tx;                 // local col 0..63
                int cc = (w - 2) * 64 + cl;            // hR col 0..127
                #pragma unroll
                for (int r = 0; r < 4; r++) {
                    float hval = h[(size_t)(r0 + r) * 128 + cc];
                    float R = sigm(acc[ct][r] + bias[ct]);
                    scr[w][(g * 4 + r) * 64 + cl] = f2bf(hval * R);
                }
            }
            // same-wave LDS: compiler orders write->read (no block barrier needed)
            int c0 = lane, c1 = lane + 64;             // chunk: row=c>>3, colc=c&7
            short8 t0 = *((const short8*)(&scr[w][(c0 >> 3) * 64 + (c0 & 7) * 8]));
            short8 t1 = *((const short8*)(&scr[w][(c1 >> 3) * 64 + (c1 & 7) * 8]));
            *((short8*)(hRb + (size_t)(rs * 16 + (c0 >> 3)) * 128 + (w - 2) * 64 + (c0 & 7) * 8)) = t0;
            *((short8*)(hRb + (size_t)(rs * 16 + (c1 >> 3)) * 128 + (w - 2) * 64 + (c1 & 7) * 8)) = t1;
        }
    }
}

// ---------------- phase B: H~ = tanh([AX|hR]@WB+bB); h0; relu ----------------
// wave w owns cols [w*32, w*32+32)
__global__ __launch_bounds__(256, 2) void k_gemmB(const ushort* __restrict__ AXb,
                                                  const ushort* __restrict__ hRb,
                                                  const float* __restrict__ h,
                                                  const ushort* __restrict__ Zt,
                                                  const ushort* __restrict__ WBs,
                                                  const float* __restrict__ bB,
                                                  float* __restrict__ out_h,
                                                  ushort* __restrict__ rl) {
    __shared__ float scrf[4][512];    // per-wave 16x32 f32 transpose scratch
    const int tid = threadIdx.x, lane = tid & 63, w = tid >> 6;
    const int tx = lane & 15, g = lane >> 4;

    short8 wf[2][8];
    #pragma unroll
    for (int ct = 0; ct < 2; ct++)
        #pragma unroll
        for (int ks = 0; ks < 8; ks++)
            wf[ct][ks] = *((const short8*)(WBs + ks * 4096 + (w * 2 + ct) * 512 + lane * 8));
    float bias[2];
    #pragma unroll
    for (int ct = 0; ct < 2; ct++) bias[ct] = bB[w * 32 + ct * 16 + tx];

    for (int rs = blockIdx.x; rs < NSUB; rs += gridDim.x) {
        const int arow = rs * 16 + tx;
        short8 axf[4], hrf[4];
        #pragma unroll
        for (int ks = 0; ks < 4; ks++) {
            axf[ks] = *((const short8*)(AXb + (size_t)arow * 128 + ks * 32 + g * 8));
            hrf[ks] = *((const short8*)(hRb + (size_t)arow * 128 + ks * 32 + g * 8));
        }
        f32x4 acc[2];
        #pragma unroll
        for (int ct = 0; ct < 2; ct++) acc[ct] = (f32x4){0.f, 0.f, 0.f, 0.f};
        #pragma unroll
        for (int ks = 0; ks < 4; ks++)
            #pragma unroll
            for (int ct = 0; ct < 2; ct++)
                acc[ct] = __builtin_amdgcn_mfma_f32_16x16x32_bf16(axf[ks], wf[ct][ks], acc[ct], 0, 0, 0);
        #pragma unroll
        for (int ks = 0; ks < 4; ks++)
            #pragma unroll
            for (int ct = 0; ct < 2; ct++)
                acc[ct] = __builtin_amdgcn_mfma_f32_16x16x32_bf16(hrf[ks], wf[ct][4 + ks], acc[ct], 0, 0, 0);

        const int r0 = rs * 16 + g * 4;
        #pragma unroll
        for (int ct = 0; ct < 2; ct++) {
            int col = w * 32 + ct * 16 + tx;
            ushort4 z4 = *((const ushort4*)(Zt + (size_t)col * NN + r0));
            float zz[4] = {bf2f(z4.x), bf2f(z4.y), bf2f(z4.z), bf2f(z4.w)};
            #pragma unroll
            for (int r = 0; r < 4; r++) {
                float hval = h[(size_t)(r0 + r) * 128 + col];
                float H = tanhf(acc[ct][r] + bias[ct]);
                float h0 = zz[r] * hval + (1.f - zz[r]) * H;
                scrf[w][(g * 4 + r) * 32 + ct * 16 + tx] = h0;
            }
        }
        // transpose-read: lane -> row=lane>>2, 8 cols at (lane&3)*8
        int row = lane >> 2, cb = (lane & 3) * 8;
        float4 h0a = *((const float4*)(&scrf[w][row * 32 + cb]));
        float4 h0b = *((const float4*)(&scrf[w][row * 32 + cb + 4]));
        size_t go = (size_t)(rs * 16 + row) * 128 + w * 32 + cb;
        *((float4*)(out_h + go)) = h0a;
        *((float4*)(out_h + go + 4)) = h0b;
        short8 rv;
        rv[0] = (short)f2bf(fmaxf(h0a.x, 0.f)); rv[1] = (short)f2bf(fmaxf(h0a.y, 0.f));
        rv[2] = (short)f2bf(fmaxf(h0a.z, 0.f)); rv[3] = (short)f2bf(fmaxf(h0a.w, 0.f));
        rv[4] = (short)f2bf(fmaxf(h0b.x, 0.f)); rv[5] = (short)f2bf(fmaxf(h0b.y, 0.f));
        rv[6] = (short)f2bf(fmaxf(h0b.z, 0.f)); rv[7] = (short)f2bf(fmaxf(h0b.w, 0.f));
        *((short8*)(rl + go)) = rv;
    }
}

// ---------------- phase C: z_out = relu(h0) @ WL + b_lin ----------------
__global__ __launch_bounds__(256, 4) void k_gemmC(const ushort* __restrict__ rl,
                                                  const ushort* __restrict__ WLs,
                                                  const float* __restrict__ b_lin,
                                                  float* __restrict__ out_z) {
    const int tid = threadIdx.x, lane = tid & 63, w = tid >> 6;
    const int tx = lane & 15, g = lane >> 4;

    short8 wf[2][4];
    #pragma unroll
    for (int ct = 0; ct < 2; ct++)
        #pragma unroll
        for (int ks = 0; ks < 4; ks++)
            wf[ct][ks] = *((const short8*)(WLs + ks * 4096 + (w * 2 + ct) * 512 + lane * 8));
    float bias[2];
    #pragma unroll
    for (int ct = 0; ct < 2; ct++) bias[ct] = b_lin[w * 32 + ct * 16 + tx];

    for (int rs = blockIdx.x; rs < NSUB; rs += gridDim.x) {
        const int arow = rs * 16 + tx;
        short8 rlf[4];
        #pragma unroll
        for (int ks = 0; ks < 4; ks++)
            rlf[ks] = *((const short8*)(rl + (size_t)arow * 128 + ks * 32 + g * 8));
        f32x4 acc[2];
        #pragma unroll
        for (int ct = 0; ct < 2; ct++) acc[ct] = (f32x4){0.f, 0.f, 0.f, 0.f};
        #pragma unroll
        for (int ks = 0; ks < 4; ks++)
            #pragma unroll
            for (int ct = 0; ct < 2; ct++)
                acc[ct] = __builtin_amdgcn_mfma_f32_16x16x32_bf16(rlf[ks], wf[ct][ks], acc[ct], 0, 0, 0);

        const int r0 = rs * 16 + g * 4;
        #pragma unroll
        for (int ct = 0; ct < 2; ct++) {
            int col = w * 32 + ct * 16 + tx;
            #pragma unroll
            for (int r = 0; r < 4; r++)
                out_z[(size_t)(r0 + r) * 128 + col] = acc[ct][r] + bias[ct];
        }
    }
}

// ---------------- launch ----------------

extern "C" void kernel_launch(void* const* d_in, const int* in_sizes, int n_in,
                              void* d_out, int out_size, void* d_ws, size_t ws_size,
                              hipStream_t stream) {
    const float* X    = (const float*)d_in[0];
    const int*   src  = (const int*)d_in[1];
    const int*   dst  = (const int*)d_in[2];
    const float* h    = (const float*)d_in[3];
    const float* Wc_z = (const float*)d_in[4];
    const float* bc_z = (const float*)d_in[5];
    const float* Wl_z = (const float*)d_in[6];
    const float* bl_z = (const float*)d_in[7];
    const float* Wc_r = (const float*)d_in[8];
    const float* bc_r = (const float*)d_in[9];
    const float* Wl_r = (const float*)d_in[10];
    const float* bl_r = (const float*)d_in[11];
    const float* Wc_h = (const float*)d_in[12];
    const float* bc_h = (const float*)d_in[13];
    const float* Wl_h = (const float*)d_in[14];
    const float* bl_h = (const float*)d_in[15];
    const float* W_lin = (const float*)d_in[16];
    const float* b_lin = (const float*)d_in[17];

    float* out_z = (float*)d_out;
    float* out_h = out_z + (size_t)NN * DD;

    // ws layout (4B words), ~55.4 MB
    float* ws = (float*)d_ws;
    float*  dinv   = ws;                           // 50048
    int*    deg    = (int*)(ws + 50048);           // 50048
    int*    cur    = (int*)(ws + 100096);          // 50048
    int*    cursor = (int*)(ws + 150144);          // 64
    int*    off    = (int*)(ws + 150208);          // 50048
    int*    csr    = (int*)(ws + 200256);          // 800064
    float*  bA     = ws + 1000320;                 // 256
    float*  bB     = ws + 1000576;                 // 128
    ushort* WAs    = (ushort*)(ws + 1000704);      // 65536 ush
    ushort* WBs    = (ushort*)(ws + 1033472);      // 32768 ush
    ushort* WLs    = (ushort*)(ws + 1049856);      // 16384 ush
    ushort* AXb    = (ushort*)(ws + 1058048);      // 6.4M ush
    ushort* Xb     = (ushort*)(ws + 4258048);      // 6.4M ush; dead after gather
    ushort* Zt     = Xb;                           //   -> reused as Zt [128][50000]
    ushort* hb     = (ushort*)(ws + 7458048);      // 6.4M ush; dead after kA
    ushort* rl     = hb;                           //   -> reused as rl [N][128]
    ushort* hRb    = (ushort*)(ws + 10658048);     // 6.4M ush

    hipMemsetAsync(deg, 0, 100160 * sizeof(int), stream);   // deg+cur+cursor
    k_cvtprep<<<12950, 256, 0, stream>>>(X, Xb, h, hb, dst, deg,
                                         Wc_z, Wl_z, bc_z, bl_z, Wc_r, Wl_r, bc_r, bl_r,
                                         Wc_h, Wl_h, bc_h, bl_h, W_lin,
                                         WAs, WBs, WLs, bA, bB);
    k_alloc<<<196, 256, 0, stream>>>(deg, off, cur, cursor, dinv);
    k_fill<<<3125, 256, 0, stream>>>(src, dst, cur, csr);
    k_gather<<<12500, 256, 0, stream>>>(Xb, csr, off, deg, dinv, AXb);
    k_gemmA<<<512, 256, 0, stream>>>(AXb, hb, h, WAs, bA, Zt, hRb);
    k_gemmB<<<512, 256, 0, stream>>>(AXb, hRb, h, Zt, WBs, bB, out_h, rl);
    k_gemmC<<<1024, 256, 0, stream>>>(rl, WLs, b_lin, out_z);
}

// Round 10
// 316.000 us; speedup vs baseline: 7.5630x; 1.0356x over previous
//
#include <hip/hip_runtime.h>
#include <math.h>

#define NN 50000
#define DD 128
#define EE 800000
#define NSUB 3125   // 16-row subtiles, exact: 50000 = 16*3125

typedef __attribute__((ext_vector_type(8))) short short8;
typedef __attribute__((ext_vector_type(4))) float f32x4;

__device__ __forceinline__ ushort f2bf(float f) {
    union { float f; unsigned u; } v; v.f = f;
    unsigned r = v.u + 0x7FFF + ((v.u >> 16) & 1);   // RNE
    return (ushort)(r >> 16);
}
__device__ __forceinline__ float bf2f(ushort u) {
    return __uint_as_float(((unsigned)u) << 16);
}
__device__ __forceinline__ float sigm(float x) { return 1.f / (1.f + expf(-x)); }

// ---------------- X convert (grid-stride) + deg count + weight prep ----------------
// blocks [0,1024): grid-stride X convert (1.6M float4) then deg atomics (800k edges)
// blocks [1024,1474): weight prep (115072 items)
__global__ void k_pre(const float* __restrict__ X, ushort* __restrict__ Xb,
                      const int* __restrict__ dste, int* __restrict__ deg,
                      const float* __restrict__ Wc_z, const float* __restrict__ Wl_z,
                      const float* __restrict__ bc_z, const float* __restrict__ bl_z,
                      const float* __restrict__ Wc_r, const float* __restrict__ Wl_r,
                      const float* __restrict__ bc_r, const float* __restrict__ bl_r,
                      const float* __restrict__ Wc_h, const float* __restrict__ Wl_h,
                      const float* __restrict__ bc_h, const float* __restrict__ bl_h,
                      const float* __restrict__ W_lin,
                      ushort* __restrict__ WAs, ushort* __restrict__ WBs,
                      ushort* __restrict__ WLs, float* __restrict__ bA,
                      float* __restrict__ bB) {
    if (blockIdx.x < 1024) {
        const int stride = 1024 * 256;
        int t0 = blockIdx.x * 256 + threadIdx.x;
        #pragma unroll 2
        for (int i = t0; i < 1600000; i += stride) {
            float4 v = ((const float4*)X)[i];
            ushort4 u;
            u.x = f2bf(v.x); u.y = f2bf(v.y); u.z = f2bf(v.z); u.w = f2bf(v.w);
            ((ushort4*)Xb)[i] = u;
        }
        #pragma unroll 2
        for (int e = t0; e < EE; e += stride)
            atomicAdd(&deg[dste[e]], 1);
        return;
    }
    int idx = (blockIdx.x - 1024) * 256 + threadIdx.x;
    // fragment-order: [ks][ctg][lane][8], lane = ((k>>3)&3)*16 + (c&15), elem k&7
    if (idx < 65536) {
        int k = idx >> 8, c = idx & 255, cc = c & 127;
        const float* Wc = (c < 128) ? Wc_z : Wc_r;
        const float* Wl = (c < 128) ? Wl_z : Wl_r;
        float v;
        if (k < 128) {
            float s = 0.f;
            #pragma unroll 8
            for (int j = 0; j < 128; j++) s += Wc[k * 128 + j] * Wl[j * 128 + cc];
            v = s;
        } else {
            v = Wl[k * 128 + cc];
        }
        WAs[(k >> 5) * 8192 + (c >> 4) * 512 + (((k >> 3) & 3) * 16 + (c & 15)) * 8 + (k & 7)] = f2bf(v);
    } else if (idx < 98304) {
        int i2 = idx - 65536;
        int k = i2 >> 7, c = i2 & 127;
        float v;
        if (k < 128) {
            float s = 0.f;
            #pragma unroll 8
            for (int j = 0; j < 128; j++) s += Wc_h[k * 128 + j] * Wl_h[j * 128 + c];
            v = s;
        } else {
            v = Wl_h[k * 128 + c];
        }
        WBs[(k >> 5) * 4096 + (c >> 4) * 512 + (((k >> 3) & 3) * 16 + (c & 15)) * 8 + (k & 7)] = f2bf(v);
    } else if (idx < 114688) {
        int i3 = idx - 98304;
        int k = i3 >> 7, c = i3 & 127;
        WLs[(k >> 5) * 4096 + (c >> 4) * 512 + (((k >> 3) & 3) * 16 + (c & 15)) * 8 + (k & 7)] = f2bf(W_lin[k * 128 + c]);
    } else if (idx < 114944) {
        int c = idx - 114688, cc = c & 127;
        const float* bc = (c < 128) ? bc_z : bc_r;
        const float* Wl = (c < 128) ? Wl_z : Wl_r;
        const float* bl = (c < 128) ? bl_z : bl_r;
        float s = bl[cc];
        #pragma unroll 8
        for (int j = 0; j < 128; j++) s += bc[j] * Wl[j * 128 + cc];
        bA[c] = s;
    } else if (idx < 115072) {
        int c = idx - 114944;
        float s = bl_h[c];
        #pragma unroll 8
        for (int j = 0; j < 128; j++) s += bc_h[j] * Wl_h[j * 128 + c];
        bB[c] = s;
    }
}

__global__ void k_alloc(const int* __restrict__ deg, int* __restrict__ off,
                        int* __restrict__ cur, int* __restrict__ cursor,
                        float* __restrict__ dinv) {
    int n = blockIdx.x * 256 + threadIdx.x;
    int lane = threadIdx.x & 63;
    int d = (n < NN) ? deg[n] : 0;
    int x = d;
    #pragma unroll
    for (int o = 1; o < 64; o <<= 1) {
        int y = __shfl_up(x, o);
        if (lane >= o) x += y;
    }
    int total = __shfl(x, 63);
    int base = 0;
    if (lane == 0) base = atomicAdd(cursor, total);
    base = __shfl(base, 0);
    if (n < NN) {
        int o2 = base + x - d;
        off[n] = o2;
        cur[n] = o2;                  // fill cursor starts at offset
        dinv[n] = rsqrtf((float)d + 1.0f);
    }
}

__global__ void k_fill(const int* __restrict__ src, const int* __restrict__ dst,
                       int* __restrict__ cur, int* __restrict__ csr) {
    int e = blockIdx.x * 256 + threadIdx.x;
    if (e < EE) {
        int slot = atomicAdd(&cur[dst[e]], 1);
        csr[slot] = src[e];
    }
}

// ---------------- gather (bf16 rows, unroll 8) ----------------
__global__ __launch_bounds__(256) void k_gather(const ushort* __restrict__ Xb,
                                                const int* __restrict__ csr,
                                                const int* __restrict__ off,
                                                const int* __restrict__ deg,
                                                const float* __restrict__ dinv,
                                                ushort* __restrict__ AXb) {
    int tid = blockIdx.x * 256 + threadIdx.x;
    int n = tid >> 6, lane = tid & 63;
    if (n >= NN) return;
    int o   = __builtin_amdgcn_readfirstlane(off[n]);
    int cnt = __builtin_amdgcn_readfirstlane(deg[n]);
    float dd = dinv[n];
    uint a = *((const uint*)(Xb + (size_t)n * 128 + lane * 2));
    float acc0 = dd * dd * __uint_as_float(a << 16);
    float acc1 = dd * dd * __uint_as_float(a & 0xffff0000u);
    int i = 0;
    for (; i + 8 <= cnt; i += 8) {
        int s[8];
        #pragma unroll
        for (int u = 0; u < 8; u++) s[u] = csr[o + i + u];
        uint v[8];
        #pragma unroll
        for (int u = 0; u < 8; u++) v[u] = *((const uint*)(Xb + (size_t)s[u] * 128 + lane * 2));
        float c[8];
        #pragma unroll
        for (int u = 0; u < 8; u++) c[u] = dinv[s[u]] * dd;
        #pragma unroll
        for (int u = 0; u < 8; u++) {
            acc0 += c[u] * __uint_as_float(v[u] << 16);
            acc1 += c[u] * __uint_as_float(v[u] & 0xffff0000u);
        }
    }
    for (; i < cnt; i++) {
        int s = csr[o + i];
        float c = dinv[s] * dd;
        uint v = *((const uint*)(Xb + (size_t)s * 128 + lane * 2));
        acc0 += c * __uint_as_float(v << 16);
        acc1 += c * __uint_as_float(v & 0xffff0000u);
    }
    ushort2 u2; u2.x = f2bf(acc0); u2.y = f2bf(acc1);
    *((ushort2*)(AXb + (size_t)n * 128 + lane * 2)) = u2;
}

// ---------------- phase A: weight-stationary, barrier-free ----------------
// 4 waves/block; wave w owns cols [w*64, w*64+64). Waves 0,1: Z (transposed out).
// Waves 2,3: hR -> row-major bf16 via per-wave LDS transpose.
// h fragments converted in-register from f32 (no hb buffer).
__global__ __launch_bounds__(256, 2) void k_gemmA(const ushort* __restrict__ AXb,
                                                  const float* __restrict__ h,
                                                  const ushort* __restrict__ WAs,
                                                  const float* __restrict__ bA,
                                                  ushort* __restrict__ Zt,
                                                  ushort* __restrict__ hRb) {
    __shared__ ushort scr[4][1024];   // per-wave 16x64 bf16 transpose scratch
    const int tid = threadIdx.x, lane = tid & 63, w = tid >> 6;
    const int tx = lane & 15, g = lane >> 4;

    short8 wf[4][8];
    #pragma unroll
    for (int ct = 0; ct < 4; ct++)
        #pragma unroll
        for (int ks = 0; ks < 8; ks++)
            wf[ct][ks] = *((const short8*)(WAs + ks * 8192 + (w * 4 + ct) * 512 + lane * 8));
    float bias[4];
    #pragma unroll
    for (int ct = 0; ct < 4; ct++) bias[ct] = bA[w * 64 + ct * 16 + tx];

    for (int rs = blockIdx.x; rs < NSUB; rs += gridDim.x) {
        const int arow = rs * 16 + tx;
        short8 axf[4], hf[4];
        #pragma unroll
        for (int ks = 0; ks < 4; ks++)
            axf[ks] = *((const short8*)(AXb + (size_t)arow * 128 + ks * 32 + g * 8));
        {
            const float4* hp = (const float4*)(h + (size_t)arow * 128);
            #pragma unroll
            for (int ks = 0; ks < 4; ks++) {
                float4 u0 = hp[ks * 8 + g * 2];
                float4 u1 = hp[ks * 8 + g * 2 + 1];
                short8 tt;
                tt[0] = (short)f2bf(u0.x); tt[1] = (short)f2bf(u0.y);
                tt[2] = (short)f2bf(u0.z); tt[3] = (short)f2bf(u0.w);
                tt[4] = (short)f2bf(u1.x); tt[5] = (short)f2bf(u1.y);
                tt[6] = (short)f2bf(u1.z); tt[7] = (short)f2bf(u1.w);
                hf[ks] = tt;
            }
        }
        f32x4 acc[4];
        #pragma unroll
        for (int ct = 0; ct < 4; ct++) acc[ct] = (f32x4){0.f, 0.f, 0.f, 0.f};
        #pragma unroll
        for (int ks = 0; ks < 4; ks++)
            #pragma unroll
            for (int ct = 0; ct < 4; ct++)
                acc[ct] = __builtin_amdgcn_mfma_f32_16x16x32_bf16(axf[ks], wf[ct][ks], acc[ct], 0, 0, 0);
        #pragma unroll
        for (int ks = 0; ks < 4; ks++)
            #pragma unroll
            for (int ct = 0; ct < 4; ct++)
                acc[ct] = __builtin_amdgcn_mfma_f32_16x16x32_bf16(hf[ks], wf[ct][4 + ks], acc[ct], 0, 0, 0);

        const int r0 = rs * 16 + g * 4;
        if (w < 2) {
            // Z: transposed layout Zt[col][row], 8B stores
            #pragma unroll
            for (int ct = 0; ct < 4; ct++) {
                int col = w * 64 + ct * 16 + tx;
                ushort4 z4;
                z4.x = f2bf(sigm(acc[ct][0] + bias[ct]));
                z4.y = f2bf(sigm(acc[ct][1] + bias[ct]));
                z4.z = f2bf(sigm(acc[ct][2] + bias[ct]));
                z4.w = f2bf(sigm(acc[ct][3] + bias[ct]));
                *((ushort4*)(Zt + (size_t)col * NN + r0)) = z4;
            }
        } else {
            // hR = h*sigmoid(R): in-wave transpose -> row-major bf16
            #pragma unroll
            for (int ct = 0; ct < 4; ct++) {
                int cl = ct * 16 + tx;                 // local col 0..63
                int cc = (w - 2) * 64 + cl;            // hR col 0..127
                #pragma unroll
                for (int r = 0; r < 4; r++) {
                    float hval = h[(size_t)(r0 + r) * 128 + cc];
                    float R = sigm(acc[ct][r] + bias[ct]);
                    scr[w][(g * 4 + r) * 64 + cl] = f2bf(hval * R);
                }
            }
            int c0 = lane, c1 = lane + 64;             // chunk: row=c>>3, colc=c&7
            short8 t0 = *((const short8*)(&scr[w][(c0 >> 3) * 64 + (c0 & 7) * 8]));
            short8 t1 = *((const short8*)(&scr[w][(c1 >> 3) * 64 + (c1 & 7) * 8]));
            *((short8*)(hRb + (size_t)(rs * 16 + (c0 >> 3)) * 128 + (w - 2) * 64 + (c0 & 7) * 8)) = t0;
            *((short8*)(hRb + (size_t)(rs * 16 + (c1 >> 3)) * 128 + (w - 2) * 64 + (c1 & 7) * 8)) = t1;
        }
    }
}

// ---------------- phase B+C fused ----------------
// Phase B: H~ = tanh([AX|hR]@WB+bB); h0 = Z*h+(1-Z)*H~ -> out_h; relu -> LDS tile
// barrier; Phase C: z_out = relu(h0) @ WL + b_lin (A-frags from LDS tile)
__global__ __launch_bounds__(256, 2) void k_gemmBC(const ushort* __restrict__ AXb,
                                                   const ushort* __restrict__ hRb,
                                                   const float* __restrict__ h,
                                                   const ushort* __restrict__ Zt,
                                                   const ushort* __restrict__ WBs,
                                                   const ushort* __restrict__ WLs,
                                                   const float* __restrict__ bB,
                                                   const float* __restrict__ b_lin,
                                                   float* __restrict__ out_h,
                                                   float* __restrict__ out_z) {
    __shared__ float scrf[4][512];    // per-wave 16x32 f32 transpose scratch (8 KB)
    __shared__ ushort rlt[2048];      // 16x128 bf16 relu tile, XOR-swizzled (4 KB)
    const int tid = threadIdx.x, lane = tid & 63, w = tid >> 6;
    const int tx = lane & 15, g = lane >> 4;

    short8 wfB[2][8], wfL[2][4];
    #pragma unroll
    for (int ct = 0; ct < 2; ct++) {
        #pragma unroll
        for (int ks = 0; ks < 8; ks++)
            wfB[ct][ks] = *((const short8*)(WBs + ks * 4096 + (w * 2 + ct) * 512 + lane * 8));
        #pragma unroll
        for (int ks = 0; ks < 4; ks++)
            wfL[ct][ks] = *((const short8*)(WLs + ks * 4096 + (w * 2 + ct) * 512 + lane * 8));
    }
    float biasB[2], biasL[2];
    #pragma unroll
    for (int ct = 0; ct < 2; ct++) {
        biasB[ct] = bB[w * 32 + ct * 16 + tx];
        biasL[ct] = b_lin[w * 32 + ct * 16 + tx];
    }

    for (int rs = blockIdx.x; rs < NSUB; rs += gridDim.x) {
        const int arow = rs * 16 + tx;
        short8 axf[4], hrf[4];
        #pragma unroll
        for (int ks = 0; ks < 4; ks++) {
            axf[ks] = *((const short8*)(AXb + (size_t)arow * 128 + ks * 32 + g * 8));
            hrf[ks] = *((const short8*)(hRb + (size_t)arow * 128 + ks * 32 + g * 8));
        }
        f32x4 acc[2];
        #pragma unroll
        for (int ct = 0; ct < 2; ct++) acc[ct] = (f32x4){0.f, 0.f, 0.f, 0.f};
        #pragma unroll
        for (int ks = 0; ks < 4; ks++)
            #pragma unroll
            for (int ct = 0; ct < 2; ct++)
                acc[ct] = __builtin_amdgcn_mfma_f32_16x16x32_bf16(axf[ks], wfB[ct][ks], acc[ct], 0, 0, 0);
        #pragma unroll
        for (int ks = 0; ks < 4; ks++)
            #pragma unroll
            for (int ct = 0; ct < 2; ct++)
                acc[ct] = __builtin_amdgcn_mfma_f32_16x16x32_bf16(hrf[ks], wfB[ct][4 + ks], acc[ct], 0, 0, 0);

        const int r0 = rs * 16 + g * 4;
        #pragma unroll
        for (int ct = 0; ct < 2; ct++) {
            int col = w * 32 + ct * 16 + tx;
            ushort4 z4 = *((const ushort4*)(Zt + (size_t)col * NN + r0));
            float zz[4] = {bf2f(z4.x), bf2f(z4.y), bf2f(z4.z), bf2f(z4.w)};
            #pragma unroll
            for (int r = 0; r < 4; r++) {
                float hval = h[(size_t)(r0 + r) * 128 + col];
                float H = tanhf(acc[ct][r] + biasB[ct]);
                float h0 = zz[r] * hval + (1.f - zz[r]) * H;
                scrf[w][(g * 4 + r) * 32 + ct * 16 + tx] = h0;
                // relu -> swizzled LDS tile (local row rr, col)
                int rr = g * 4 + r;
                *((ushort*)((char*)rlt + rr * 256 + ((col * 2) ^ ((rr & 7) << 4)))) = f2bf(fmaxf(h0, 0.f));
            }
        }
        // out_h via per-wave transpose-read (coalesced f32 stores)
        {
            int row = lane >> 2, cb = (lane & 3) * 8;
            float4 h0a = *((const float4*)(&scrf[w][row * 32 + cb]));
            float4 h0b = *((const float4*)(&scrf[w][row * 32 + cb + 4]));
            size_t go = (size_t)(rs * 16 + row) * 128 + w * 32 + cb;
            *((float4*)(out_h + go)) = h0a;
            *((float4*)(out_h + go + 4)) = h0b;
        }
        __syncthreads();   // rlt complete across waves

        // ---- phase C ----
        f32x4 accC[2];
        #pragma unroll
        for (int ct = 0; ct < 2; ct++) accC[ct] = (f32x4){0.f, 0.f, 0.f, 0.f};
        #pragma unroll
        for (int ks = 0; ks < 4; ks++) {
            short8 a = *((const short8*)((const char*)rlt + tx * 256 + ((ks * 64 + g * 16) ^ ((tx & 7) << 4))));
            #pragma unroll
            for (int ct = 0; ct < 2; ct++)
                accC[ct] = __builtin_amdgcn_mfma_f32_16x16x32_bf16(a, wfL[ct][ks], accC[ct], 0, 0, 0);
        }
        #pragma unroll
        for (int ct = 0; ct < 2; ct++) {
            int col = w * 32 + ct * 16 + tx;
            #pragma unroll
            for (int r = 0; r < 4; r++)
                out_z[(size_t)(r0 + r) * 128 + col] = accC[ct][r] + biasL[ct];
        }
        __syncthreads();   // protect rlt from next iteration's writes
    }
}

// ---------------- launch ----------------

extern "C" void kernel_launch(void* const* d_in, const int* in_sizes, int n_in,
                              void* d_out, int out_size, void* d_ws, size_t ws_size,
                              hipStream_t stream) {
    const float* X    = (const float*)d_in[0];
    const int*   src  = (const int*)d_in[1];
    const int*   dst  = (const int*)d_in[2];
    const float* h    = (const float*)d_in[3];
    const float* Wc_z = (const float*)d_in[4];
    const float* bc_z = (const float*)d_in[5];
    const float* Wl_z = (const float*)d_in[6];
    const float* bl_z = (const float*)d_in[7];
    const float* Wc_r = (const float*)d_in[8];
    const float* bc_r = (const float*)d_in[9];
    const float* Wl_r = (const float*)d_in[10];
    const float* bl_r = (const float*)d_in[11];
    const float* Wc_h = (const float*)d_in[12];
    const float* bc_h = (const float*)d_in[13];
    const float* Wl_h = (const float*)d_in[14];
    const float* bl_h = (const float*)d_in[15];
    const float* W_lin = (const float*)d_in[16];
    const float* b_lin = (const float*)d_in[17];

    float* out_z = (float*)d_out;
    float* out_h = out_z + (size_t)NN * DD;

    // ws layout (4B words)
    float* ws = (float*)d_ws;
    float*  dinv   = ws;                           // 50048
    int*    deg    = (int*)(ws + 50048);           // 50048
    int*    cur    = (int*)(ws + 100096);          // 50048
    int*    cursor = (int*)(ws + 150144);          // 64
    int*    off    = (int*)(ws + 150208);          // 50048
    int*    csr    = (int*)(ws + 200256);          // 800064
    float*  bA     = ws + 1000320;                 // 256
    float*  bB     = ws + 1000576;                 // 128
    ushort* WAs    = (ushort*)(ws + 1000704);      // 65536 ush
    ushort* WBs    = (ushort*)(ws + 1033472);      // 32768 ush
    ushort* WLs    = (ushort*)(ws + 1049856);      // 16384 ush
    ushort* AXb    = (ushort*)(ws + 1058048);      // 6.4M ush
    ushort* Xb     = (ushort*)(ws + 4258048);      // 6.4M ush; dead after gather
    ushort* Zt     = Xb;                           //   -> reused as Zt [128][50000]
    ushort* hRb    = (ushort*)(ws + 7458048);      // 6.4M ush

    hipMemsetAsync(deg, 0, 100160 * sizeof(int), stream);   // deg+cur+cursor
    k_pre<<<1474, 256, 0, stream>>>(X, Xb, dst, deg,
                                    Wc_z, Wl_z, bc_z, bl_z, Wc_r, Wl_r, bc_r, bl_r,
                                    Wc_h, Wl_h, bc_h, bl_h, W_lin,
                                    WAs, WBs, WLs, bA, bB);
    k_alloc<<<196, 256, 0, stream>>>(deg, off, cur, cursor, dinv);
    k_fill<<<3125, 256, 0, stream>>>(src, dst, cur, csr);
    k_gather<<<12500, 256, 0, stream>>>(Xb, csr, off, deg, dinv, AXb);
    k_gemmA<<<512, 256, 0, stream>>>(AXb, h, WAs, bA, Zt, hRb);
    k_gemmBC<<<512, 256, 0, stream>>>(AXb, hRb, h, Zt, WBs, WLs, bB, b_lin, out_h, out_z);
}

// Round 12
// 286.959 us; speedup vs baseline: 8.3284x; 1.1012x over previous
//
#include <hip/hip_runtime.h>
#include <math.h>

#define NN 50000
#define DD 128
#define EE 800000
#define NSUB 3125   // 16-row subtiles, exact: 50000 = 16*3125

typedef __attribute__((ext_vector_type(8))) short short8;
typedef __attribute__((ext_vector_type(4))) float f32x4;

__device__ __forceinline__ ushort f2bf(float f) {
    union { float f; unsigned u; } v; v.f = f;
    unsigned r = v.u + 0x7FFF + ((v.u >> 16) & 1);   // RNE
    return (ushort)(r >> 16);
}
__device__ __forceinline__ float bf2f(ushort u) {
    return __uint_as_float(((unsigned)u) << 16);
}
__device__ __forceinline__ float sigm(float x) { return 1.f / (1.f + expf(-x)); }

// ---------------- X convert + ELL fill + weight prep (one kernel) ----------------
// blocks [0,1024): grid-stride X convert (1.6M float4) then ELL fill (800k edges,
//                  ONE atomic pass: slot=atomicAdd(cnt[d]); ell[d*64+slot]=src)
// blocks [1024,1474): weight prep (115072 items)
__global__ void k_pre(const float* __restrict__ X, ushort* __restrict__ Xb,
                      const int* __restrict__ srce, const int* __restrict__ dste,
                      int* __restrict__ cnt, int* __restrict__ ell,
                      const float* __restrict__ Wc_z, const float* __restrict__ Wl_z,
                      const float* __restrict__ bc_z, const float* __restrict__ bl_z,
                      const float* __restrict__ Wc_r, const float* __restrict__ Wl_r,
                      const float* __restrict__ bc_r, const float* __restrict__ bl_r,
                      const float* __restrict__ Wc_h, const float* __restrict__ Wl_h,
                      const float* __restrict__ bc_h, const float* __restrict__ bl_h,
                      const float* __restrict__ W_lin,
                      ushort* __restrict__ WAs, ushort* __restrict__ WBs,
                      ushort* __restrict__ WLs, float* __restrict__ bA,
                      float* __restrict__ bB) {
    if (blockIdx.x < 1024) {
        const int stride = 1024 * 256;
        int t0 = blockIdx.x * 256 + threadIdx.x;
        #pragma unroll 2
        for (int i = t0; i < 1600000; i += stride) {
            float4 v = ((const float4*)X)[i];
            ushort4 u;
            u.x = f2bf(v.x); u.y = f2bf(v.y); u.z = f2bf(v.z); u.w = f2bf(v.w);
            ((ushort4*)Xb)[i] = u;
        }
        #pragma unroll 2
        for (int e = t0; e < EE; e += stride) {
            int d = dste[e];
            int slot = atomicAdd(&cnt[d], 1);
            ell[(d << 6) + slot] = srce[e];
        }
        return;
    }
    int idx = (blockIdx.x - 1024) * 256 + threadIdx.x;
    // fragment-order: [ks][ctg][lane][8], lane = ((k>>3)&3)*16 + (c&15), elem k&7
    if (idx < 65536) {
        int k = idx >> 8, c = idx & 255, cc = c & 127;
        const float* Wc = (c < 128) ? Wc_z : Wc_r;
        const float* Wl = (c < 128) ? Wl_z : Wl_r;
        float v;
        if (k < 128) {
            float s = 0.f;
            #pragma unroll 8
            for (int j = 0; j < 128; j++) s += Wc[k * 128 + j] * Wl[j * 128 + cc];
            v = s;
        } else {
            v = Wl[k * 128 + cc];
        }
        WAs[(k >> 5) * 8192 + (c >> 4) * 512 + (((k >> 3) & 3) * 16 + (c & 15)) * 8 + (k & 7)] = f2bf(v);
    } else if (idx < 98304) {
        int i2 = idx - 65536;
        int k = i2 >> 7, c = i2 & 127;
        float v;
        if (k < 128) {
            float s = 0.f;
            #pragma unroll 8
            for (int j = 0; j < 128; j++) s += Wc_h[k * 128 + j] * Wl_h[j * 128 + c];
            v = s;
        } else {
            v = Wl_h[k * 128 + c];
        }
        WBs[(k >> 5) * 4096 + (c >> 4) * 512 + (((k >> 3) & 3) * 16 + (c & 15)) * 8 + (k & 7)] = f2bf(v);
    } else if (idx < 114688) {
        int i3 = idx - 98304;
        int k = i3 >> 7, c = i3 & 127;
        WLs[(k >> 5) * 4096 + (c >> 4) * 512 + (((k >> 3) & 3) * 16 + (c & 15)) * 8 + (k & 7)] = f2bf(W_lin[k * 128 + c]);
    } else if (idx < 114944) {
        int c = idx - 114688, cc = c & 127;
        const float* bc = (c < 128) ? bc_z : bc_r;
        const float* Wl = (c < 128) ? Wl_z : Wl_r;
        const float* bl = (c < 128) ? bl_z : bl_r;
        float s = bl[cc];
        #pragma unroll 8
        for (int j = 0; j < 128; j++) s += bc[j] * Wl[j * 128 + cc];
        bA[c] = s;
    } else if (idx < 115072) {
        int c = idx - 114944;
        float s = bl_h[c];
        #pragma unroll 8
        for (int j = 0; j < 128; j++) s += bc_h[j] * Wl_h[j * 128 + c];
        bB[c] = s;
    }
}

// dinv from the fill counters (deg == cnt after k_pre)
__global__ void k_dinv(const int* __restrict__ cnt, float* __restrict__ dinv) {
    int n = blockIdx.x * 256 + threadIdx.x;
    if (n < NN) dinv[n] = rsqrtf((float)cnt[n] + 1.0f);
}

// ---------------- gather (ELL lists, bf16 rows, unroll 8) ----------------
__global__ __launch_bounds__(256) void k_gather(const ushort* __restrict__ Xb,
                                                const int* __restrict__ ell,
                                                const int* __restrict__ cnt,
                                                const float* __restrict__ dinv,
                                                ushort* __restrict__ AXb) {
    int tid = blockIdx.x * 256 + threadIdx.x;
    int n = tid >> 6, lane = tid & 63;
    if (n >= NN) return;
    int o = n << 6;                                       // ELL base (wave-uniform)
    int c_ = __builtin_amdgcn_readfirstlane(cnt[n]);
    float dd = dinv[n];
    uint a = *((const uint*)(Xb + (size_t)n * 128 + lane * 2));
    float acc0 = dd * dd * __uint_as_float(a << 16);
    float acc1 = dd * dd * __uint_as_float(a & 0xffff0000u);
    int i = 0;
    for (; i + 8 <= c_; i += 8) {
        int s[8];
        #pragma unroll
        for (int u = 0; u < 8; u++) s[u] = ell[o + i + u];
        uint v[8];
        #pragma unroll
        for (int u = 0; u < 8; u++) v[u] = *((const uint*)(Xb + (size_t)s[u] * 128 + lane * 2));
        float c[8];
        #pragma unroll
        for (int u = 0; u < 8; u++) c[u] = dinv[s[u]] * dd;
        #pragma unroll
        for (int u = 0; u < 8; u++) {
            acc0 += c[u] * __uint_as_float(v[u] << 16);
            acc1 += c[u] * __uint_as_float(v[u] & 0xffff0000u);
        }
    }
    for (; i < c_; i++) {
        int s = ell[o + i];
        float c = dinv[s] * dd;
        uint v = *((const uint*)(Xb + (size_t)s * 128 + lane * 2));
        acc0 += c * __uint_as_float(v << 16);
        acc1 += c * __uint_as_float(v & 0xffff0000u);
    }
    ushort2 u2; u2.x = f2bf(acc0); u2.y = f2bf(acc1);
    *((ushort2*)(AXb + (size_t)n * 128 + lane * 2)) = u2;
}

// ---------------- phase A: weight-stationary, barrier-free ----------------
__global__ __launch_bounds__(256, 2) void k_gemmA(const ushort* __restrict__ AXb,
                                                  const float* __restrict__ h,
                                                  const ushort* __restrict__ WAs,
                                                  const float* __restrict__ bA,
                                                  ushort* __restrict__ Zt,
                                                  ushort* __restrict__ hRb) {
    __shared__ ushort scr[4][1024];   // per-wave 16x64 bf16 transpose scratch
    const int tid = threadIdx.x, lane = tid & 63, w = tid >> 6;
    const int tx = lane & 15, g = lane >> 4;

    short8 wf[4][8];
    #pragma unroll
    for (int ct = 0; ct < 4; ct++)
        #pragma unroll
        for (int ks = 0; ks < 8; ks++)
            wf[ct][ks] = *((const short8*)(WAs + ks * 8192 + (w * 4 + ct) * 512 + lane * 8));
    float bias[4];
    #pragma unroll
    for (int ct = 0; ct < 4; ct++) bias[ct] = bA[w * 64 + ct * 16 + tx];

    for (int rs = blockIdx.x; rs < NSUB; rs += gridDim.x) {
        const int arow = rs * 16 + tx;
        short8 axf[4], hf[4];
        #pragma unroll
        for (int ks = 0; ks < 4; ks++)
            axf[ks] = *((const short8*)(AXb + (size_t)arow * 128 + ks * 32 + g * 8));
        {
            const float4* hp = (const float4*)(h + (size_t)arow * 128);
            #pragma unroll
            for (int ks = 0; ks < 4; ks++) {
                float4 u0 = hp[ks * 8 + g * 2];
                float4 u1 = hp[ks * 8 + g * 2 + 1];
                short8 tt;
                tt[0] = (short)f2bf(u0.x); tt[1] = (short)f2bf(u0.y);
                tt[2] = (short)f2bf(u0.z); tt[3] = (short)f2bf(u0.w);
                tt[4] = (short)f2bf(u1.x); tt[5] = (short)f2bf(u1.y);
                tt[6] = (short)f2bf(u1.z); tt[7] = (short)f2bf(u1.w);
                hf[ks] = tt;
            }
        }
        f32x4 acc[4];
        #pragma unroll
        for (int ct = 0; ct < 4; ct++) acc[ct] = (f32x4){0.f, 0.f, 0.f, 0.f};
        #pragma unroll
        for (int ks = 0; ks < 4; ks++)
            #pragma unroll
            for (int ct = 0; ct < 4; ct++)
                acc[ct] = __builtin_amdgcn_mfma_f32_16x16x32_bf16(axf[ks], wf[ct][ks], acc[ct], 0, 0, 0);
        #pragma unroll
        for (int ks = 0; ks < 4; ks++)
            #pragma unroll
            for (int ct = 0; ct < 4; ct++)
                acc[ct] = __builtin_amdgcn_mfma_f32_16x16x32_bf16(hf[ks], wf[ct][4 + ks], acc[ct], 0, 0, 0);

        const int r0 = rs * 16 + g * 4;
        if (w < 2) {
            // Z: transposed layout Zt[col][row], 8B stores
            #pragma unroll
            for (int ct = 0; ct < 4; ct++) {
                int col = w * 64 + ct * 16 + tx;
                ushort4 z4;
                z4.x = f2bf(sigm(acc[ct][0] + bias[ct]));
                z4.y = f2bf(sigm(acc[ct][1] + bias[ct]));
                z4.z = f2bf(sigm(acc[ct][2] + bias[ct]));
                z4.w = f2bf(sigm(acc[ct][3] + bias[ct]));
                *((ushort4*)(Zt + (size_t)col * NN + r0)) = z4;
            }
        } else {
            // hR = h*sigmoid(R): in-wave transpose -> row-major bf16
            #pragma unroll
            for (int ct = 0; ct < 4; ct++) {
                int cl = ct * 16 + tx;                 // local col 0..63
                int cc = (w - 2) * 64 + cl;            // hR col 0..127
                #pragma unroll
                for (int r = 0; r < 4; r++) {
                    float hval = h[(size_t)(r0 + r) * 128 + cc];
                    float R = sigm(acc[ct][r] + bias[ct]);
                    scr[w][(g * 4 + r) * 64 + cl] = f2bf(hval * R);
                }
            }
            int c0 = lane, c1 = lane + 64;             // chunk: row=c>>3, colc=c&7
            short8 t0 = *((const short8*)(&scr[w][(c0 >> 3) * 64 + (c0 & 7) * 8]));
            short8 t1 = *((const short8*)(&scr[w][(c1 >> 3) * 64 + (c1 & 7) * 8]));
            *((short8*)(hRb + (size_t)(rs * 16 + (c0 >> 3)) * 128 + (w - 2) * 64 + (c0 & 7) * 8)) = t0;
            *((short8*)(hRb + (size_t)(rs * 16 + (c1 >> 3)) * 128 + (w - 2) * 64 + (c1 & 7) * 8)) = t1;
        }
    }
}

// ---------------- phase B+C fused ----------------
__global__ __launch_bounds__(256, 2) void k_gemmBC(const ushort* __restrict__ AXb,
                                                   const ushort* __restrict__ hRb,
                                                   const float* __restrict__ h,
                                                   const ushort* __restrict__ Zt,
                                                   const ushort* __restrict__ WBs,
                                                   const ushort* __restrict__ WLs,
                                                   const float* __restrict__ bB,
                                                   const float* __restrict__ b_lin,
                                                   float* __restrict__ out_h,
                                                   float* __restrict__ out_z) {
    __shared__ float scrf[4][512];    // per-wave 16x32 f32 transpose scratch (8 KB)
    __shared__ ushort rlt[2048];      // 16x128 bf16 relu tile, XOR-swizzled (4 KB)
    const int tid = threadIdx.x, lane = tid & 63, w = tid >> 6;
    const int tx = lane & 15, g = lane >> 4;

    short8 wfB[2][8], wfL[2][4];
    #pragma unroll
    for (int ct = 0; ct < 2; ct++) {
        #pragma unroll
        for (int ks = 0; ks < 8; ks++)
            wfB[ct][ks] = *((const short8*)(WBs + ks * 4096 + (w * 2 + ct) * 512 + lane * 8));
        #pragma unroll
        for (int ks = 0; ks < 4; ks++)
            wfL[ct][ks] = *((const short8*)(WLs + ks * 4096 + (w * 2 + ct) * 512 + lane * 8));
    }
    float biasB[2], biasL[2];
    #pragma unroll
    for (int ct = 0; ct < 2; ct++) {
        biasB[ct] = bB[w * 32 + ct * 16 + tx];
        biasL[ct] = b_lin[w * 32 + ct * 16 + tx];
    }

    for (int rs = blockIdx.x; rs < NSUB; rs += gridDim.x) {
        const int arow = rs * 16 + tx;
        short8 axf[4], hrf[4];
        #pragma unroll
        for (int ks = 0; ks < 4; ks++) {
            axf[ks] = *((const short8*)(AXb + (size_t)arow * 128 + ks * 32 + g * 8));
            hrf[ks] = *((const short8*)(hRb + (size_t)arow * 128 + ks * 32 + g * 8));
        }
        f32x4 acc[2];
        #pragma unroll
        for (int ct = 0; ct < 2; ct++) acc[ct] = (f32x4){0.f, 0.f, 0.f, 0.f};
        #pragma unroll
        for (int ks = 0; ks < 4; ks++)
            #pragma unroll
            for (int ct = 0; ct < 2; ct++)
                acc[ct] = __builtin_amdgcn_mfma_f32_16x16x32_bf16(axf[ks], wfB[ct][ks], acc[ct], 0, 0, 0);
        #pragma unroll
        for (int ks = 0; ks < 4; ks++)
            #pragma unroll
            for (int ct = 0; ct < 2; ct++)
                acc[ct] = __builtin_amdgcn_mfma_f32_16x16x32_bf16(hrf[ks], wfB[ct][4 + ks], acc[ct], 0, 0, 0);

        const int r0 = rs * 16 + g * 4;
        #pragma unroll
        for (int ct = 0; ct < 2; ct++) {
            int col = w * 32 + ct * 16 + tx;
            ushort4 z4 = *((const ushort4*)(Zt + (size_t)col * NN + r0));
            float zz[4] = {bf2f(z4.x), bf2f(z4.y), bf2f(z4.z), bf2f(z4.w)};
            #pragma unroll
            for (int r = 0; r < 4; r++) {
                float hval = h[(size_t)(r0 + r) * 128 + col];
                float H = tanhf(acc[ct][r] + biasB[ct]);
                float h0 = zz[r] * hval + (1.f - zz[r]) * H;
                scrf[w][(g * 4 + r) * 32 + ct * 16 + tx] = h0;
                int rr = g * 4 + r;
                *((ushort*)((char*)rlt + rr * 256 + ((col * 2) ^ ((rr & 7) << 4)))) = f2bf(fmaxf(h0, 0.f));
            }
        }
        // out_h via per-wave transpose-read (coalesced f32 stores)
        {
            int row = lane >> 2, cb = (lane & 3) * 8;
            float4 h0a = *((const float4*)(&scrf[w][row * 32 + cb]));
            float4 h0b = *((const float4*)(&scrf[w][row * 32 + cb + 4]));
            size_t go = (size_t)(rs * 16 + row) * 128 + w * 32 + cb;
            *((float4*)(out_h + go)) = h0a;
            *((float4*)(out_h + go + 4)) = h0b;
        }
        __syncthreads();   // rlt complete across waves

        // ---- phase C ----
        f32x4 accC[2];
        #pragma unroll
        for (int ct = 0; ct < 2; ct++) accC[ct] = (f32x4){0.f, 0.f, 0.f, 0.f};
        #pragma unroll
        for (int ks = 0; ks < 4; ks++) {
            short8 a = *((const short8*)((const char*)rlt + tx * 256 + ((ks * 64 + g * 16) ^ ((tx & 7) << 4))));
            #pragma unroll
            for (int ct = 0; ct < 2; ct++)
                accC[ct] = __builtin_amdgcn_mfma_f32_16x16x32_bf16(a, wfL[ct][ks], accC[ct], 0, 0, 0);
        }
        #pragma unroll
        for (int ct = 0; ct < 2; ct++) {
            int col = w * 32 + ct * 16 + tx;
            #pragma unroll
            for (int r = 0; r < 4; r++)
                out_z[(size_t)(r0 + r) * 128 + col] = accC[ct][r] + biasL[ct];
        }
        __syncthreads();   // protect rlt from next iteration's writes
    }
}

// ---------------- launch ----------------

extern "C" void kernel_launch(void* const* d_in, const int* in_sizes, int n_in,
                              void* d_out, int out_size, void* d_ws, size_t ws_size,
                              hipStream_t stream) {
    const float* X    = (const float*)d_in[0];
    const int*   src  = (const int*)d_in[1];
    const int*   dst  = (const int*)d_in[2];
    const float* h    = (const float*)d_in[3];
    const float* Wc_z = (const float*)d_in[4];
    const float* bc_z = (const float*)d_in[5];
    const float* Wl_z = (const float*)d_in[6];
    const float* bl_z = (const float*)d_in[7];
    const float* Wc_r = (const float*)d_in[8];
    const float* bc_r = (const float*)d_in[9];
    const float* Wl_r = (const float*)d_in[10];
    const float* bl_r = (const float*)d_in[11];
    const float* Wc_h = (const float*)d_in[12];
    const float* bc_h = (const float*)d_in[13];
    const float* Wl_h = (const float*)d_in[14];
    const float* bl_h = (const float*)d_in[15];
    const float* W_lin = (const float*)d_in[16];
    const float* b_lin = (const float*)d_in[17];

    float* out_z = (float*)d_out;
    float* out_h = out_z + (size_t)NN * DD;

    // ws layout (4B words)
    float* ws = (float*)d_ws;
    float*  dinv = ws;                             // 50048
    int*    cnt  = (int*)(ws + 50048);             // 50048
    int*    ell  = (int*)(ws + 100096);            // 3,200,000 (50000 x 64)
    float*  bA   = ws + 3300160;                   // 256
    float*  bB   = ws + 3300416;                   // 128
    ushort* WAs  = (ushort*)(ws + 3300544);        // 65536 ush
    ushort* WBs  = (ushort*)(ws + 3333312);        // 32768 ush
    ushort* WLs  = (ushort*)(ws + 3349696);        // 16384 ush
    ushort* AXb  = (ushort*)(ws + 3357888);        // 6.4M ush
    ushort* Xb   = (ushort*)(ws + 6557888);        // 6.4M ush; dead after gather
    ushort* Zt   = Xb;                             //   -> reused as Zt [128][50000]
    ushort* hRb  = (ushort*)(ws + 9757888);        // 6.4M ush

    hipMemsetAsync(cnt, 0, 50048 * sizeof(int), stream);
    k_pre<<<1474, 256, 0, stream>>>(X, Xb, src, dst, cnt, ell,
                                    Wc_z, Wl_z, bc_z, bl_z, Wc_r, Wl_r, bc_r, bl_r,
                                    Wc_h, Wl_h, bc_h, bl_h, W_lin,
                                    WAs, WBs, WLs, bA, bB);
    k_dinv<<<196, 256, 0, stream>>>(cnt, dinv);
    k_gather<<<12500, 256, 0, stream>>>(Xb, ell, cnt, dinv, AXb);
    k_gemmA<<<512, 256, 0, stream>>>(AXb, h, WAs, bA, Zt, hRb);
    k_gemmBC<<<512, 256, 0, stream>>>(AXb, hRb, h, Zt, WBs, WLs, bB, b_lin, out_h, out_z);
}